// Round 3
// baseline (941.504 us; speedup 1.0000x reference)
//
#include <hip/hip_runtime.h>
#include <stddef.h>

typedef unsigned short u16;
typedef unsigned int u32;

#define B_ 4
#define T_ 2048
#define C_ 1024
#define E_ 8
#define H_ 4096
#define NTOK (B_ * T_)     // 8192
#define NPAIR (NTOK * 2)   // 16384
#define BM 256
#define BN 256
#define BK 64              // k-tile (bf16 elements); row = 128 B
#define KSPLIT 2           // phase2 K-split (atomics make this free)
#define MAXTILES 72        // ceil((16384 + 8*255)/256)
#define MAXROWS (MAXTILES * BM)  // 18432

typedef __bf16 bf16x8 __attribute__((ext_vector_type(8)));
typedef float f32x4 __attribute__((ext_vector_type(4)));

#define UNROLL _Pragma("unroll")

__device__ __forceinline__ u16 f2bf(float f) {
    union { float f; u32 u; } c;
    c.f = f;
    u32 r = c.u + 0x7FFFu + ((c.u >> 16) & 1u);  // round-to-nearest-even
    return (u16)(r >> 16);
}

// async global->LDS, 16B per lane; LDS dest = wave-uniform base + lane*16
__device__ __forceinline__ void gld16(const void* g, void* l) {
    __builtin_amdgcn_global_load_lds(
        (const __attribute__((address_space(1))) u32*)g,
        (__attribute__((address_space(3))) u32*)l, 16, 0, 0);
}

// ---------------- LayerNorm: h = bf16(LN(x)), out = x; fused expert count ----
__global__ __launch_bounds__(256) void ln_kernel(
    const float* __restrict__ x, const float* __restrict__ gamma,
    const float* __restrict__ beta, float* __restrict__ out,
    u16* __restrict__ h, const int* __restrict__ winners,
    int* __restrict__ counts) {
    const int token = blockIdx.x;
    const int t = threadIdx.x;
    if (t < 2) atomicAdd(&counts[winners[token * 2 + t]], 1);
    const float* xr = x + (size_t)token * C_;
    float4 v = *(const float4*)(xr + t * 4);
    float s = v.x + v.y + v.z + v.w;
    float ss = v.x * v.x + v.y * v.y + v.z * v.z + v.w * v.w;
    #pragma unroll
    for (int off = 32; off > 0; off >>= 1) {
        s += __shfl_down(s, off);
        ss += __shfl_down(ss, off);
    }
    __shared__ float ws_s[4], ws_q[4];
    const int wave = t >> 6, lane = t & 63;
    if (lane == 0) { ws_s[wave] = s; ws_q[wave] = ss; }
    __syncthreads();
    float S = ws_s[0] + ws_s[1] + ws_s[2] + ws_s[3];
    float Q = ws_q[0] + ws_q[1] + ws_q[2] + ws_q[3];
    float mu = S * (1.0f / C_);
    float var = Q * (1.0f / C_) - mu * mu;
    float rstd = rsqrtf(var + 1e-5f);
    float4 g = *(const float4*)(gamma + t * 4);
    float4 b = *(const float4*)(beta + t * 4);
    ushort4 hv;
    hv.x = f2bf((v.x - mu) * rstd * g.x + b.x);
    hv.y = f2bf((v.y - mu) * rstd * g.y + b.y);
    hv.z = f2bf((v.z - mu) * rstd * g.z + b.z);
    hv.w = f2bf((v.w - mu) * rstd * g.w + b.w);
    *(float4*)(out + (size_t)token * C_ + t * 4) = v;  // out = x (residual base)
    *(ushort4*)(h + (size_t)token * C_ + t * 4) = hv;
}

// ---------------- Weight convert+transpose: fp32 [E][K][N] -> bf16 [E][N][K] --
// PERM: source k-row permuted per 64-block by phi(r)=((r&3)<<4)|(r>>2), matching
// the gemm1 epilogue's packed hidden layout (only used for W2).
template <bool PERM>
__global__ __launch_bounds__(256) void convert_transpose(
    const float* __restrict__ in, u16* __restrict__ outp, int K, int N) {
    const int e = blockIdx.z;
    const int k0 = blockIdx.y * 64, n0 = blockIdx.x * 64;
    const int tx = threadIdx.x & 15, ty = threadIdx.x >> 4;  // 16 x 16
    __shared__ float t[64][69];  // pitch 69: 2-way max bank aliasing on reads
    const float* src = in + (size_t)e * K * N;
    u16* dst = outp + (size_t)e * N * K;
    #pragma unroll
    for (int i = 0; i < 4; ++i) {
        int r = ty + i * 16;  // LDS row (= dst k-offset)
        int kr = PERM ? (((r & 3) << 4) | (r >> 2)) : r;  // src k-offset
        float4 v = *(const float4*)(src + (size_t)(k0 + kr) * N + n0 + tx * 4);
        t[r][tx * 4 + 0] = v.x;
        t[r][tx * 4 + 1] = v.y;
        t[r][tx * 4 + 2] = v.z;
        t[r][tx * 4 + 3] = v.w;
    }
    __syncthreads();
    #pragma unroll
    for (int i = 0; i < 4; ++i) {
        int nl = ty + i * 16;
        ushort4 o;
        o.x = f2bf(t[tx * 4 + 0][nl]);
        o.y = f2bf(t[tx * 4 + 1][nl]);
        o.z = f2bf(t[tx * 4 + 2][nl]);
        o.w = f2bf(t[tx * 4 + 3][nl]);
        *(ushort4*)(dst + (size_t)(n0 + nl) * K + k0 + tx * 4) = o;
    }
}

// ---------------- Expert bucketing (pad to BM=256) ----------------
__global__ __launch_bounds__(256) void offsets_kernel(
    const int* __restrict__ counts, int* __restrict__ padded_off,
    int* __restrict__ tile_expert) {
    __shared__ int po[E_ + 1];
    if (threadIdx.x == 0) {
        int off = 0;
        po[0] = 0;
        padded_off[0] = 0;
        for (int e = 0; e < E_; ++e) {
            off += ((counts[e] + 255) >> 8) << 8;
            po[e + 1] = off;
            padded_off[e + 1] = off;
        }
    }
    __syncthreads();
    const int t = threadIdx.x;
    if (t < MAXTILES) {
        int r = t * BM;
        int e = -1;
        if (r < po[E_]) {
            e = 0;
            while (r >= po[e + 1]) ++e;
        }
        tile_expert[t] = e;
    }
}

__global__ void place_kernel(const int* __restrict__ winners, const float* __restrict__ wts,
                             const int* __restrict__ padded_off, int* __restrict__ pos,
                             int* __restrict__ token_id, float* __restrict__ pair_w) {
    int p = blockIdx.x * blockDim.x + threadIdx.x;
    if (p >= NPAIR) return;
    int e = winners[p];
    int slot = padded_off[e] + atomicAdd(&pos[e], 1);
    token_id[slot] = p >> 1;
    pair_w[slot] = wts[p];
}

// ---------------- Grouped GEMM: 256x256 tile, 8 waves, 8-phase schedule -------
// T3+T4 port (m201/m248 template): 4 quadrant-phases per K-tile, 1 half-tile
// staged per phase, counted s_waitcnt vmcnt(4) ONCE per K-tile (never 0 in the
// loop), raw s_barrier pairs per phase, setprio(1) around each 16-MFMA cluster.
// LDS halves are consumption-ordered: A-half(h) = rows read by quadrant q_m==h
// {wr*128 + h*64 + [0,64)}; B-half(h) = rows read by q_n==h {wc*64+h*32+[0,32)}.
// Every staged half targets a region whose last ds_read was >=1 barrier earlier
// (race-free by construction). Global-side XOR chunk swizzle kept (0-conflict).
// PHASE2=false: hidden[r,:] = bf16(relu(h[tok(r)] @ W1T[e]^T)^2)  K=1024, N=4096
//               hidden K-dim stored permuted per 64-block: p64 = lrow*4 + ni
// PHASE2=true : out[tok(r),:] += pair_w[r] * (hidden[r] @ W2T[e]^T) K=4096/KSPLIT
template <bool PHASE2>
__global__ __launch_bounds__(512, 2) void gemm_kernel(
    const u16* __restrict__ Amat, const u16* __restrict__ Bmat,
    const int* __restrict__ token_id, const float* __restrict__ pair_w,
    const int* __restrict__ tile_expert, u16* __restrict__ hidden,
    float* __restrict__ out, const u16* __restrict__ zeropage) {
    constexpr int Kdim = PHASE2 ? H_ : C_;               // row pitch of A and B
    constexpr int KRANGE = PHASE2 ? (H_ / KSPLIT) : C_;  // per-block K extent
    constexpr int NT = KRANGE / BK;                      // 32 or 16 k-tiles
    constexpr int NWGX = PHASE2 ? (C_ / BN) : (H_ / BN); // 4 or 16
    constexpr int NWG = NWGX * MAXTILES;                 // 288 or 1152 (%8==0)

    int bid = blockIdx.y * NWGX + blockIdx.x;
    bid = (bid & 7) * (NWG >> 3) + (bid >> 3);
    const int ct = bid % NWGX;
    const int rt = bid / NWGX;

    const int e = tile_expert[rt];
    if (e < 0) return;
    const int tid = threadIdx.x;
    const int w = tid >> 6;      // wave 0..7
    const int lane = tid & 63;
    const int sub = lane >> 3;
    const u32 koffB = (u32)(((lane & 7) ^ sub) * 16);  // global-side swizzle
    const int n0 = ct * BN;
    const int kbase = PHASE2 ? blockIdx.z * KRANGE : 0;
    const char* Abase = (const char*)Amat;
    const char* Bbase = (const char*)(Bmat + (size_t)e * H_ * C_);
    const char* zp = (const char*)zeropage;

    // Staging address setup. Instr (h,j): A global row = j*128 + h*64 + ws,
    // B global n-row = n0 + (j*2 + (ws>>5))*64 + h*32 + (ws&31), ws = w*8+sub.
    const int ws = w * 8 + sub;
    u32 aoff[4];
    bool aval[4];
    u32 boff[4];
    UNROLL
    for (int h = 0; h < 2; ++h) {
        UNROLL
        for (int j = 0; j < 2; ++j) {
            const int idx = h * 2 + j;
            const int grow = rt * BM + j * 128 + h * 64 + ws;
            if (PHASE2) {
                aval[idx] = true;
                aoff[idx] = (u32)(((size_t)grow * Kdim + kbase) * 2) + koffB;
            } else {
                int tok = token_id[grow];
                aval[idx] = tok >= 0;
                aoff[idx] = (u32)((size_t)(tok < 0 ? 0 : tok) * Kdim * 2) + koffB;
            }
            const int gn = n0 + (j * 2 + (ws >> 5)) * 64 + h * 32 + (ws & 31);
            boff[idx] = (u32)(((size_t)gn * Kdim + kbase) * 2) + koffB;
        }
    }

    extern __shared__ u16 smem[];  // 2 bufs x (A 2x16KB + B 2x16KB) = 128 KB
    const int wr = w >> 2, wc = w & 3;   // wave tile: rows wr*128, cols wc*64
    const int lrow = lane & 15;
    const int quad = lane >> 4;
    const int rsw = lrow & 7;            // read-side swizzle key

    f32x4 acc[8][4] = {};
    bf16x8 af[4][2], b0[2][2], b1[2][2];

// stage one instr of A/B half H, instr J, k-tile KT into buffer DB
#define STA(H, J, KT, DB)                                                     \
    gld16(((KT) < NT && aval[(H) * 2 + (J)])                                  \
              ? Abase + aoff[(H) * 2 + (J)] + (size_t)(KT) * 128 : zp,        \
          smem + (DB) * 32768 + (H) * 8192 + ((J) * 64 + w * 8) * 64)
#define STB(H, J, KT, DB)                                                     \
    gld16(((KT) < NT) ? Bbase + boff[(H) * 2 + (J)] + (size_t)(KT) * 128 : zp,\
          smem + (DB) * 32768 + 16384 + (H) * 8192 + ((J) * 64 + w * 8) * 64)
#define RDA(QM, CB)                                                           \
    UNROLL for (int mi = 0; mi < 4; ++mi)                                     \
    UNROLL for (int kk = 0; kk < 2; ++kk)                                     \
        af[mi][kk] = *(const bf16x8*)&smem[(CB) * 32768 + (QM) * 8192 +       \
            (wr * 64 + mi * 16 + lrow) * 64 + (((kk * 4 + quad) ^ rsw) * 8)]
#define RDB(QN, CB, BV)                                                       \
    UNROLL for (int ni = 0; ni < 2; ++ni)                                     \
    UNROLL for (int kk = 0; kk < 2; ++kk)                                     \
        BV[ni][kk] = *(const bf16x8*)&smem[(CB) * 32768 + 16384 +             \
            (QN) * 8192 + (wc * 32 + ni * 16 + lrow) * 64 +                   \
            (((kk * 4 + quad) ^ rsw) * 8)]
#define MM(QM, QN, BV)                                                        \
    __builtin_amdgcn_s_setprio(1);                                            \
    UNROLL for (int mi = 0; mi < 4; ++mi)                                     \
    UNROLL for (int ni = 0; ni < 2; ++ni)                                     \
    UNROLL for (int kk = 0; kk < 2; ++kk)                                     \
        acc[(QM) * 4 + mi][(QN) * 2 + ni] =                                   \
            __builtin_amdgcn_mfma_f32_16x16x32_bf16(                          \
                af[mi][kk], BV[ni][kk], acc[(QM) * 4 + mi][(QN) * 2 + ni],    \
                0, 0, 0);                                                     \
    __builtin_amdgcn_s_setprio(0)
#define BARR __builtin_amdgcn_s_barrier()
#define VM4 asm volatile("s_waitcnt vmcnt(4)" ::: "memory")

// One K-tile = 4 quadrant phases. CB = compute buffer, OB = other buffer.
// Stage schedule (per analysis): p0: A-half1(T+1)->OB, p1: B-half1(T+1)->OB,
// p2: A-half0(T+2)->CB, p3: B-half0(T+2)->CB + vmcnt(4).
#define KTILE(CB, OB, TT)                                                     \
    {                                                                         \
        RDA(0, CB); RDB(0, CB, b0);                                           \
        STA(1, 0, (TT) + 1, OB); STA(1, 1, (TT) + 1, OB);                     \
        BARR; MM(0, 0, b0); BARR;                                             \
        RDB(1, CB, b1);                                                       \
        STB(1, 0, (TT) + 1, OB); STB(1, 1, (TT) + 1, OB);                     \
        BARR; MM(0, 1, b1); BARR;                                             \
        RDA(1, CB);                                                           \
        STA(0, 0, (TT) + 2, CB); STA(0, 1, (TT) + 2, CB);                     \
        BARR; MM(1, 0, b0); BARR;                                             \
        STB(0, 0, (TT) + 2, CB); STB(0, 1, (TT) + 2, CB);                     \
        BARR; MM(1, 1, b1);                                                   \
        VM4; BARR;                                                            \
    }

    // Prologue: tile0 fully -> buf0, tile1 halves A0,B0 -> buf1 (6 halves,
    // 12 loads); vmcnt(4) leaves tile1's 2 halves in flight.
    STA(0, 0, 0, 0); STA(0, 1, 0, 0); STB(0, 0, 0, 0); STB(0, 1, 0, 0);
    STA(1, 0, 0, 0); STA(1, 1, 0, 0); STB(1, 0, 0, 0); STB(1, 1, 0, 0);
    STA(0, 0, 1, 1); STA(0, 1, 1, 1); STB(0, 0, 1, 1); STB(0, 1, 1, 1);
    VM4; BARR;

    for (int t = 0; t < NT; t += 2) {
        KTILE(0, 1, t);
        KTILE(1, 0, t + 1);
    }
    // Drain trailing (zeropage) stages before this wave may retire.
    asm volatile("s_waitcnt vmcnt(0)" ::: "memory");

#undef STA
#undef STB
#undef RDA
#undef RDB
#undef MM
#undef BARR
#undef VM4
#undef KTILE

    if (!PHASE2) {
        // Packed store: per (mi,j)-row, lane's 4 ni-values go to permuted
        // k' = n0 + wc*64 + lrow*4 + ni  -> one ushort4 (8 B) store.
        UNROLL
        for (int mi = 0; mi < 8; ++mi) {
            const int rbase = rt * BM + wr * 128 + mi * 16 + quad * 4;
            UNROLL
            for (int j = 0; j < 4; ++j) {
                ushort4 o;
                float v0 = fmaxf(acc[mi][0][j], 0.0f);
                float v1 = fmaxf(acc[mi][1][j], 0.0f);
                float v2 = fmaxf(acc[mi][2][j], 0.0f);
                float v3 = fmaxf(acc[mi][3][j], 0.0f);
                o.x = f2bf(v0 * v0);
                o.y = f2bf(v1 * v1);
                o.z = f2bf(v2 * v2);
                o.w = f2bf(v3 * v3);
                *(ushort4*)&hidden[(size_t)(rbase + j) * H_ + n0 + wc * 64 +
                                   lrow * 4] = o;
            }
        }
    } else {
        UNROLL
        for (int mi = 0; mi < 8; ++mi) {
            const int rbase = rt * BM + wr * 128 + mi * 16 + quad * 4;
            UNROLL
            for (int j = 0; j < 4; ++j) {
                const int grow = rbase + j;
                const int tok = token_id[grow];
                if (tok < 0) continue;
                const float pw = pair_w[grow];
                UNROLL
                for (int ni = 0; ni < 4; ++ni) {
                    const int col = n0 + wc * 64 + ni * 16 + lrow;
                    atomicAdd(&out[(size_t)tok * C_ + col], pw * acc[mi][ni][j]);
                }
            }
        }
    }
}

// ---------------- Launch ----------------
extern "C" void kernel_launch(void* const* d_in, const int* in_sizes, int n_in,
                              void* d_out, int out_size, void* d_ws, size_t ws_size,
                              hipStream_t stream) {
    const float* x = (const float*)d_in[0];
    const float* weights = (const float*)d_in[1];
    const float* gamma = (const float*)d_in[2];
    const float* beta = (const float*)d_in[3];
    const float* W1 = (const float*)d_in[4];
    const float* W2 = (const float*)d_in[5];
    const int* winners = (const int*)d_in[6];
    float* out = (float*)d_out;

    char* ws = (char*)d_ws;
    const size_t SZ_H = (size_t)NTOK * C_ * 2;           // 16 MB
    const size_t SZ_HID = (size_t)MAXROWS * H_ * 2;      // 151 MB
    const size_t SZ_WT = (size_t)E_ * H_ * C_ * 2;       // 64 MB each
    const size_t OFF_HID = SZ_H;
    const size_t OFF_W1T = OFF_HID + SZ_HID;
    const size_t OFF_W2T = OFF_W1T + SZ_WT;
    const size_t OFF_META = OFF_W2T + SZ_WT;

    u16* h = (u16*)ws;
    u16* hidden = (u16*)(ws + OFF_HID);
    u16* W1T = (u16*)(ws + OFF_W1T);
    u16* W2T = (u16*)(ws + OFF_W2T);
    int* meta = (int*)(ws + OFF_META);
    int* counts = meta;            // [0,8)
    int* pos = meta + 8;           // [8,16)
    int* padded_off = meta + 16;   // [16,32)
    u16* zeropage = (u16*)(meta + 32);  // [32,48) 64 B, 16B-aligned
    int* tile_expert = meta + 48;  // [48,120)
    int* token_id = meta + 192;
    float* pair_w = (float*)(meta + 192 + MAXROWS);

    constexpr int GEMM_LDS = 2 * (BM * BK + BN * BK) * 2;  // 131072 B
    static int attr_done = 0;
    if (!attr_done) {
        hipFuncSetAttribute(reinterpret_cast<const void*>(&gemm_kernel<false>),
                            hipFuncAttributeMaxDynamicSharedMemorySize, GEMM_LDS);
        hipFuncSetAttribute(reinterpret_cast<const void*>(&gemm_kernel<true>),
                            hipFuncAttributeMaxDynamicSharedMemorySize, GEMM_LDS);
        attr_done = 1;
    }

    hipMemsetAsync(meta, 0, 192 * sizeof(int), stream);
    hipMemsetAsync(token_id, 0xFF, (size_t)MAXROWS * sizeof(int), stream);

    ln_kernel<<<NTOK, 256, 0, stream>>>(x, gamma, beta, out, h, winners, counts);
    convert_transpose<false><<<dim3(H_ / 64, C_ / 64, E_), 256, 0, stream>>>(W1, W1T, C_, H_);
    convert_transpose<true><<<dim3(C_ / 64, H_ / 64, E_), 256, 0, stream>>>(W2, W2T, H_, C_);
    offsets_kernel<<<1, 256, 0, stream>>>(counts, padded_off, tile_expert);
    place_kernel<<<NPAIR / 256, 256, 0, stream>>>(winners, weights, padded_off, pos,
                                                  token_id, pair_w);
    gemm_kernel<false><<<dim3(H_ / BN, MAXTILES), 512, GEMM_LDS, stream>>>(
        h, W1T, token_id, pair_w, tile_expert, hidden, nullptr, zeropage);
    gemm_kernel<true><<<dim3(C_ / BN, MAXTILES, KSPLIT), 512, GEMM_LDS, stream>>>(
        hidden, W2T, token_id, pair_w, tile_expert, nullptr, out, zeropage);
}

// Round 4
// 872.768 us; speedup vs baseline: 1.0788x; 1.0788x over previous
//
#include <hip/hip_runtime.h>
#include <stddef.h>

typedef unsigned short u16;
typedef unsigned int u32;

#define B_ 4
#define T_ 2048
#define C_ 1024
#define E_ 8
#define H_ 4096
#define NTOK (B_ * T_)     // 8192
#define NPAIR (NTOK * 2)   // 16384
#define BM 128
#define BN 128
#define BK 64              // k-tile (bf16 elements); row = 128 B
#define KSPLIT 2           // phase2 K-split (atomics make this free)
#define MAXTILES 136       // ceil((16384 + 8*127)/128)
#define MAXROWS (MAXTILES * 128)  // 17408

typedef __bf16 bf16x8 __attribute__((ext_vector_type(8)));
typedef float f32x4 __attribute__((ext_vector_type(4)));
typedef u16 u16x8 __attribute__((ext_vector_type(8)));

__device__ __forceinline__ u16 f2bf(float f) {
    union { float f; u32 u; } c;
    c.f = f;
    u32 r = c.u + 0x7FFFu + ((c.u >> 16) & 1u);  // round-to-nearest-even
    return (u16)(r >> 16);
}

// async global->LDS, 16B per lane; LDS dest = wave-uniform base + lane*16
__device__ __forceinline__ void gld16(const void* g, void* l) {
    __builtin_amdgcn_global_load_lds(
        (const __attribute__((address_space(1))) u32*)g,
        (__attribute__((address_space(3))) u32*)l, 16, 0, 0);
}

// ---------------- LayerNorm: h = bf16(LN(x)), out = x; fused expert count ----
__global__ __launch_bounds__(256) void ln_kernel(
    const float* __restrict__ x, const float* __restrict__ gamma,
    const float* __restrict__ beta, float* __restrict__ out,
    u16* __restrict__ h, const int* __restrict__ winners,
    int* __restrict__ counts) {
    const int token = blockIdx.x;
    const int t = threadIdx.x;
    if (t < 2) atomicAdd(&counts[winners[token * 2 + t]], 1);
    const float* xr = x + (size_t)token * C_;
    float4 v = *(const float4*)(xr + t * 4);
    float s = v.x + v.y + v.z + v.w;
    float ss = v.x * v.x + v.y * v.y + v.z * v.z + v.w * v.w;
    #pragma unroll
    for (int off = 32; off > 0; off >>= 1) {
        s += __shfl_down(s, off);
        ss += __shfl_down(ss, off);
    }
    __shared__ float ws_s[4], ws_q[4];
    const int wave = t >> 6, lane = t & 63;
    if (lane == 0) { ws_s[wave] = s; ws_q[wave] = ss; }
    __syncthreads();
    float S = ws_s[0] + ws_s[1] + ws_s[2] + ws_s[3];
    float Q = ws_q[0] + ws_q[1] + ws_q[2] + ws_q[3];
    float mu = S * (1.0f / C_);
    float var = Q * (1.0f / C_) - mu * mu;
    float rstd = rsqrtf(var + 1e-5f);
    float4 g = *(const float4*)(gamma + t * 4);
    float4 b = *(const float4*)(beta + t * 4);
    ushort4 hv;
    hv.x = f2bf((v.x - mu) * rstd * g.x + b.x);
    hv.y = f2bf((v.y - mu) * rstd * g.y + b.y);
    hv.z = f2bf((v.z - mu) * rstd * g.z + b.z);
    hv.w = f2bf((v.w - mu) * rstd * g.w + b.w);
    *(float4*)(out + (size_t)token * C_ + t * 4) = v;  // out = x (residual base)
    *(ushort4*)(h + (size_t)token * C_ + t * 4) = hv;
}

// ---------------- Weight convert+transpose: fp32 [E][K][N] -> bf16 [E][N][K] --
// Rewritten for streaming BW: tile = 64 k-rows x 256 n-cols.
//  - global reads: per wave-instr, ONE full 1KB row segment (64 lanes x 16B)
//  - global writes: per wave-instr, 8 full dst rows x 128B, fully contiguous
//  - LDS: bf16 on load (32KB), pitch 258 u16; every access pattern is at the
//    uniform bank minimum (verified: load-writes 4 words/bank for b64-class,
//    store-reads 2/bank for b32) -> conflict-free
//  - u32 LDS reads deliver two adjacent dst rows at once (32 reads/thread)
// PERM: source k-row permuted per 64-block by phi(r)=((r&3)<<4)|(r>>2), matching
// the gemm1 epilogue's packed hidden layout (only used for W2).
template <bool PERM>
__global__ __launch_bounds__(256) void convert_transpose(
    const float* __restrict__ in, u16* __restrict__ outp, int K, int N) {
    const int e = blockIdx.z;
    const int k0 = blockIdx.y * 64, n0 = blockIdx.x * 256;
    const int t = threadIdx.x;
    __shared__ u16 sm[64 * 258];  // [k][n], pitch 258 u16 (~33 KB)
    const float* src = in + (size_t)e * K * N;
    u16* dst = outp + (size_t)e * N * K;
    const int cw = t & 63;        // n-chunk (float4 granularity) within row
    const int rw = t >> 6;        // wave index = row offset within pass
    #pragma unroll
    for (int p = 0; p < 16; ++p) {
        const int r = p * 4 + rw;
        const int kr = PERM ? (((r & 3) << 4) | (r >> 2)) : r;  // src k-offset
        float4 v = *(const float4*)(src + (size_t)(k0 + kr) * N + n0 + cw * 4);
        const int base = r * 258 + cw * 4;
        sm[base + 0] = f2bf(v.x);
        sm[base + 1] = f2bf(v.y);
        sm[base + 2] = f2bf(v.z);
        sm[base + 3] = f2bf(v.w);
    }
    __syncthreads();
    const u32* smw = (const u32*)sm;
    const int c = t & 7;          // 16B k-chunk within a dst row
    const int ro = t >> 3;        // row-pair offset within pass (0..31)
    #pragma unroll
    for (int p = 0; p < 4; ++p) {
        const int np = p * 32 + ro;          // dst rows 2np, 2np+1
        u16x8 lo, hi;
        #pragma unroll
        for (int m = 0; m < 8; ++m) {
            u32 wv = smw[(c * 8 + m) * 129 + np];  // {sm[k][2np], sm[k][2np+1]}
            lo[m] = (u16)(wv & 0xFFFFu);
            hi[m] = (u16)(wv >> 16);
        }
        *(u16x8*)(dst + (size_t)(n0 + 2 * np) * K + k0 + c * 8) = lo;
        *(u16x8*)(dst + (size_t)(n0 + 2 * np + 1) * K + k0 + c * 8) = hi;
    }
}

// ---------------- Expert bucketing: offsets fused into place ----------------
// Each block recomputes the tiny 8-expert padded prefix from counts in shared;
// block 0 additionally fills tile_expert. Saves a dependent dispatch.
__global__ __launch_bounds__(256) void place_kernel(
    const int* __restrict__ winners, const float* __restrict__ wts,
    const int* __restrict__ counts, int* __restrict__ pos,
    int* __restrict__ token_id, float* __restrict__ pair_w,
    int* __restrict__ tile_expert) {
    __shared__ int po[E_ + 1];
    if (threadIdx.x == 0) {
        int off = 0;
        po[0] = 0;
        #pragma unroll
        for (int e = 0; e < E_; ++e) {
            off += ((counts[e] + 127) >> 7) << 7;
            po[e + 1] = off;
        }
    }
    __syncthreads();
    if (blockIdx.x == 0 && threadIdx.x < MAXTILES) {
        int r = threadIdx.x * 128;
        int ee = -1;
        if (r < po[E_]) {
            ee = 0;
            while (r >= po[ee + 1]) ++ee;
        }
        tile_expert[threadIdx.x] = ee;
    }
    int p = blockIdx.x * blockDim.x + threadIdx.x;
    if (p >= NPAIR) return;
    int e = winners[p];
    int slot = po[e] + atomicAdd(&pos[e], 1);
    token_id[slot] = p >> 1;
    pair_w[slot] = wts[p];
}

// ---------------- Grouped GEMM, m97-style async staging + XOR swizzle ---------
// Round-2 proven structure, byte-identical (4 blocks/CU, implicit wave overlap,
// T1 XCD-bijective swizzle, PHASE2 K-split).
// PHASE2=false: hidden[r,:] = bf16(relu(h[tok(r)] @ W1T[e]^T)^2)  K=1024, N=4096
//               hidden K-dim stored permuted: p64 = lrow*4 + ni
// PHASE2=true : out[tok(r),:] += pair_w[r] * (hidden[r] @ W2T[e]^T) K=4096/KSPLIT
template <bool PHASE2>
__global__ __launch_bounds__(256, 4) void gemm_kernel(
    const u16* __restrict__ Amat, const u16* __restrict__ Bmat,
    const int* __restrict__ token_id, const float* __restrict__ pair_w,
    const int* __restrict__ tile_expert, u16* __restrict__ hidden,
    float* __restrict__ out, const u16* __restrict__ zeropage) {
    constexpr int Kdim = PHASE2 ? H_ : C_;            // row pitch of A and B
    constexpr int KRANGE = PHASE2 ? (H_ / KSPLIT) : C_;  // per-block K extent
    constexpr int NWGX = PHASE2 ? (C_ / BN) : (H_ / BN); // 8 or 32
    constexpr int NWG = NWGX * MAXTILES;              // 1088 or 4352 (%8==0)

    int bid = blockIdx.y * NWGX + blockIdx.x;
    bid = (bid & 7) * (NWG >> 3) + (bid >> 3);
    const int ct = bid % NWGX;
    const int rt = bid / NWGX;

    const int e = tile_expert[rt];
    if (e < 0) return;
    const int tid = threadIdx.x;
    const int w = tid >> 6;      // wave 0..3
    const int lane = tid & 63;
    const int n0 = ct * BN;
    const int kbase = PHASE2 ? blockIdx.z * KRANGE : 0;
    const u16* Bb = Bmat + (size_t)e * H_ * C_;

    __shared__ u16 As[BM * BK];  // 16 KB, [row][k], row = 128 B
    __shared__ u16 Bs[BN * BK];  // 16 KB, [n][k]

    const int sub = lane >> 3;
    const size_t koffB = (size_t)(((lane & 7) ^ sub) * 16);

    const char* abase[4];
    bool aval[4];
    const char* bbase[4];
    u16* adst[4];
    u16* bdst[4];
    #pragma unroll
    for (int j = 0; j < 4; ++j) {
        const int lrow32 = w * 32 + j * 8 + sub;
        const int grow = rt * BM + lrow32;
        if (PHASE2) {
            aval[j] = true;
            abase[j] = (const char*)(Amat + (size_t)grow * Kdim + kbase) + koffB;
        } else {
            int tok = token_id[grow];
            aval[j] = tok >= 0;
            abase[j] = (const char*)(Amat + (size_t)(tok < 0 ? 0 : tok) * Kdim) + koffB;
        }
        bbase[j] = (const char*)(Bb + (size_t)(n0 + lrow32) * Kdim + kbase) + koffB;
        adst[j] = &As[(w * 32 + j * 8) * BK];
        bdst[j] = &Bs[(w * 32 + j * 8) * BK];
    }

    const int wr = w >> 1, wc = w & 1;
    const int lrow = lane & 15;
    const int quad = lane >> 4;
    const int rsw = lrow & 7;  // read-side swizzle key

    f32x4 acc[4][4] = {};

    for (int k0 = 0; k0 < KRANGE; k0 += BK) {
        __syncthreads();
        const size_t kb = (size_t)k0 * 2;
        #pragma unroll
        for (int j = 0; j < 4; ++j)
            gld16(aval[j] ? abase[j] + kb : (const char*)zeropage, adst[j]);
        #pragma unroll
        for (int j = 0; j < 4; ++j)
            gld16(bbase[j] + kb, bdst[j]);
        __syncthreads();
        #pragma unroll
        for (int kk = 0; kk < 2; ++kk) {
            bf16x8 af[4], bfv[4];
            #pragma unroll
            for (int mi = 0; mi < 4; ++mi) {
                int row = wr * 64 + mi * 16 + lrow;
                int pch = (kk * 4 + quad) ^ rsw;
                af[mi] = *(const bf16x8*)&As[row * BK + pch * 8];
            }
            #pragma unroll
            for (int ni = 0; ni < 4; ++ni) {
                int row = wc * 64 + ni * 16 + lrow;
                int pch = (kk * 4 + quad) ^ rsw;
                bfv[ni] = *(const bf16x8*)&Bs[row * BK + pch * 8];
            }
            #pragma unroll
            for (int mi = 0; mi < 4; ++mi)
                #pragma unroll
                for (int ni = 0; ni < 4; ++ni)
                    acc[mi][ni] = __builtin_amdgcn_mfma_f32_16x16x32_bf16(
                        af[mi], bfv[ni], acc[mi][ni], 0, 0, 0);
        }
    }

    if (!PHASE2) {
        #pragma unroll
        for (int mi = 0; mi < 4; ++mi) {
            int rbase = rt * BM + wr * 64 + mi * 16 + quad * 4;
            #pragma unroll
            for (int j = 0; j < 4; ++j) {
                ushort4 o;
                float v0 = fmaxf(acc[mi][0][j], 0.0f);
                float v1 = fmaxf(acc[mi][1][j], 0.0f);
                float v2 = fmaxf(acc[mi][2][j], 0.0f);
                float v3 = fmaxf(acc[mi][3][j], 0.0f);
                o.x = f2bf(v0 * v0);
                o.y = f2bf(v1 * v1);
                o.z = f2bf(v2 * v2);
                o.w = f2bf(v3 * v3);
                *(ushort4*)&hidden[(size_t)(rbase + j) * H_ + n0 + wc * 64 + lrow * 4] = o;
            }
        }
    } else {
        #pragma unroll
        for (int mi = 0; mi < 4; ++mi) {
            int rbase = rt * BM + wr * 64 + mi * 16 + quad * 4;
            #pragma unroll
            for (int j = 0; j < 4; ++j) {
                int grow = rbase + j;
                int tok = token_id[grow];
                if (tok < 0) continue;
                float pw = pair_w[grow];
                #pragma unroll
                for (int ni = 0; ni < 4; ++ni) {
                    int col = n0 + wc * 64 + ni * 16 + lrow;
                    atomicAdd(&out[(size_t)tok * C_ + col], pw * acc[mi][ni][j]);
                }
            }
        }
    }
}

// ---------------- Launch ----------------
extern "C" void kernel_launch(void* const* d_in, const int* in_sizes, int n_in,
                              void* d_out, int out_size, void* d_ws, size_t ws_size,
                              hipStream_t stream) {
    const float* x = (const float*)d_in[0];
    const float* weights = (const float*)d_in[1];
    const float* gamma = (const float*)d_in[2];
    const float* beta = (const float*)d_in[3];
    const float* W1 = (const float*)d_in[4];
    const float* W2 = (const float*)d_in[5];
    const int* winners = (const int*)d_in[6];
    float* out = (float*)d_out;

    char* ws = (char*)d_ws;
    const size_t SZ_H = (size_t)NTOK * C_ * 2;           // 16 MB
    const size_t SZ_HID = (size_t)MAXROWS * H_ * 2;      // 136 MB
    const size_t SZ_WT = (size_t)E_ * H_ * C_ * 2;       // 64 MB each
    const size_t OFF_HID = SZ_H;
    const size_t OFF_W1T = OFF_HID + SZ_HID;
    const size_t OFF_W2T = OFF_W1T + SZ_WT;
    const size_t OFF_META = OFF_W2T + SZ_WT;

    u16* h = (u16*)ws;
    u16* hidden = (u16*)(ws + OFF_HID);
    u16* W1T = (u16*)(ws + OFF_W1T);
    u16* W2T = (u16*)(ws + OFF_W2T);
    int* meta = (int*)(ws + OFF_META);
    int* counts = meta;            // [0,8)
    int* pos = meta + 8;           // [8,16)
    // [16,32) reserved
    u16* zeropage = (u16*)(meta + 32);  // [32,48) 64 B, 16B-aligned
    int* tile_expert = meta + 48;  // [48,184)
    int* token_id = meta + 192;
    float* pair_w = (float*)(meta + 192 + MAXROWS);

    hipMemsetAsync(meta, 0, 192 * sizeof(int), stream);
    hipMemsetAsync(token_id, 0xFF, (size_t)MAXROWS * sizeof(int), stream);

    ln_kernel<<<NTOK, 256, 0, stream>>>(x, gamma, beta, out, h, winners, counts);
    convert_transpose<false><<<dim3(H_ / 256, C_ / 64, E_), 256, 0, stream>>>(W1, W1T, C_, H_);
    convert_transpose<true><<<dim3(C_ / 256, H_ / 64, E_), 256, 0, stream>>>(W2, W2T, H_, C_);
    place_kernel<<<NPAIR / 256, 256, 0, stream>>>(winners, weights, counts, pos,
                                                  token_id, pair_w, tile_expert);
    gemm_kernel<false><<<dim3(H_ / BN, MAXTILES), 256, 0, stream>>>(
        h, W1T, token_id, pair_w, tile_expert, hidden, nullptr, zeropage);
    gemm_kernel<true><<<dim3(C_ / BN, MAXTILES, KSPLIT), 256, 0, stream>>>(
        hidden, W2T, token_id, pair_w, tile_expert, nullptr, out, zeropage);
}

// Round 5
// 728.725 us; speedup vs baseline: 1.2920x; 1.1977x over previous
//
#include <hip/hip_runtime.h>
#include <stddef.h>

typedef unsigned short u16;
typedef unsigned int u32;

#define B_ 4
#define T_ 2048
#define C_ 1024
#define E_ 8
#define H_ 4096
#define NTOK (B_ * T_)     // 8192
#define NPAIR (NTOK * 2)   // 16384
#define BM 128
#define BN 128
#define BK 64              // k-tile (bf16 elements); row = 128 B
#define KSPLIT 2           // phase2 K-split (atomics make this free)
#define MAXTILES 136       // ceil((16384 + 8*127)/128)
#define MAXROWS (MAXTILES * 128)  // 17408

typedef __bf16 bf16x8 __attribute__((ext_vector_type(8)));
typedef float f32x4 __attribute__((ext_vector_type(4)));
typedef u16 u16x8 __attribute__((ext_vector_type(8)));

__device__ __forceinline__ u16 f2bf(float f) {
    union { float f; u32 u; } c;
    c.f = f;
    u32 r = c.u + 0x7FFFu + ((c.u >> 16) & 1u);  // round-to-nearest-even
    return (u16)(r >> 16);
}

// async global->LDS, 16B per lane; LDS dest = wave-uniform base + lane*16
__device__ __forceinline__ void gld16(const void* g, void* l) {
    __builtin_amdgcn_global_load_lds(
        (const __attribute__((address_space(1))) u32*)g,
        (__attribute__((address_space(3))) u32*)l, 16, 0, 0);
}

// ---------------- LayerNorm: h = bf16(LN(x)), out = x (pure streaming) -------
// Counting removed: 16K atomicAdds onto ONE cache line (counts[0..8)) from
// 8192 blocks serialized at L2 and was the prime dark-time suspect.
__global__ __launch_bounds__(256) void ln_kernel(
    const float* __restrict__ x, const float* __restrict__ gamma,
    const float* __restrict__ beta, float* __restrict__ out,
    u16* __restrict__ h) {
    const int token = blockIdx.x;
    const int t = threadIdx.x;
    const float* xr = x + (size_t)token * C_;
    float4 v = *(const float4*)(xr + t * 4);
    float s = v.x + v.y + v.z + v.w;
    float ss = v.x * v.x + v.y * v.y + v.z * v.z + v.w * v.w;
    #pragma unroll
    for (int off = 32; off > 0; off >>= 1) {
        s += __shfl_down(s, off);
        ss += __shfl_down(ss, off);
    }
    __shared__ float ws_s[4], ws_q[4];
    const int wave = t >> 6, lane = t & 63;
    if (lane == 0) { ws_s[wave] = s; ws_q[wave] = ss; }
    __syncthreads();
    float S = ws_s[0] + ws_s[1] + ws_s[2] + ws_s[3];
    float Q = ws_q[0] + ws_q[1] + ws_q[2] + ws_q[3];
    float mu = S * (1.0f / C_);
    float var = Q * (1.0f / C_) - mu * mu;
    float rstd = rsqrtf(var + 1e-5f);
    float4 g = *(const float4*)(gamma + t * 4);
    float4 b = *(const float4*)(beta + t * 4);
    ushort4 hv;
    hv.x = f2bf((v.x - mu) * rstd * g.x + b.x);
    hv.y = f2bf((v.y - mu) * rstd * g.y + b.y);
    hv.z = f2bf((v.z - mu) * rstd * g.z + b.z);
    hv.w = f2bf((v.w - mu) * rstd * g.w + b.w);
    *(float4*)(out + (size_t)token * C_ + t * 4) = v;  // out = x (residual base)
    *(ushort4*)(h + (size_t)token * C_ + t * 4) = hv;
}

// ---------------- Expert count: LDS histogram, 8 global atomics/block --------
// Replaces 16,384 same-line global atomics with 64 blocks x 8 = 512.
__global__ __launch_bounds__(256) void count_kernel(
    const int* __restrict__ winners, int* __restrict__ counts) {
    __shared__ int lc[E_];
    if (threadIdx.x < E_) lc[threadIdx.x] = 0;
    __syncthreads();
    const int p = blockIdx.x * 256 + threadIdx.x;
    atomicAdd(&lc[winners[p]], 1);  // LDS atomic (per-CU, fast)
    __syncthreads();
    if (threadIdx.x < E_) {
        int c = lc[threadIdx.x];
        if (c) atomicAdd(&counts[threadIdx.x], c);
    }
}

// ---------------- Weight convert+transpose: fp32 [E][K][N] -> bf16 [E][N][K] --
// Streaming layout: tile = 64 k-rows x 256 n-cols; 1KB contiguous wave reads,
// 128B-per-row contiguous writes, conflict-free pitch-258 LDS.
// PERM: source k-row permuted per 64-block by phi(r)=((r&3)<<4)|(r>>2), matching
// the gemm1 epilogue's packed hidden layout (only used for W2).
template <bool PERM>
__global__ __launch_bounds__(256) void convert_transpose(
    const float* __restrict__ in, u16* __restrict__ outp, int K, int N) {
    const int e = blockIdx.z;
    const int k0 = blockIdx.y * 64, n0 = blockIdx.x * 256;
    const int t = threadIdx.x;
    __shared__ u16 sm[64 * 258];  // [k][n], pitch 258 u16 (~33 KB)
    const float* src = in + (size_t)e * K * N;
    u16* dst = outp + (size_t)e * N * K;
    const int cw = t & 63;        // n-chunk (float4 granularity) within row
    const int rw = t >> 6;        // wave index = row offset within pass
    #pragma unroll
    for (int p = 0; p < 16; ++p) {
        const int r = p * 4 + rw;
        const int kr = PERM ? (((r & 3) << 4) | (r >> 2)) : r;  // src k-offset
        float4 v = *(const float4*)(src + (size_t)(k0 + kr) * N + n0 + cw * 4);
        const int base = r * 258 + cw * 4;
        sm[base + 0] = f2bf(v.x);
        sm[base + 1] = f2bf(v.y);
        sm[base + 2] = f2bf(v.z);
        sm[base + 3] = f2bf(v.w);
    }
    __syncthreads();
    const u32* smw = (const u32*)sm;
    const int c = t & 7;          // 16B k-chunk within a dst row
    const int ro = t >> 3;        // row-pair offset within pass (0..31)
    #pragma unroll
    for (int p = 0; p < 4; ++p) {
        const int np = p * 32 + ro;          // dst rows 2np, 2np+1
        u16x8 lo, hi;
        #pragma unroll
        for (int m = 0; m < 8; ++m) {
            u32 wv = smw[(c * 8 + m) * 129 + np];  // {sm[k][2np], sm[k][2np+1]}
            lo[m] = (u16)(wv & 0xFFFFu);
            hi[m] = (u16)(wv >> 16);
        }
        *(u16x8*)(dst + (size_t)(n0 + 2 * np) * K + k0 + c * 8) = lo;
        *(u16x8*)(dst + (size_t)(n0 + 2 * np + 1) * K + k0 + c * 8) = hi;
    }
}

// ---------------- Placement: block-aggregated reservation --------------------
// Per-block LDS histogram gives each thread an intra-block rank; ONE global
// atomicAdd per (block, expert) reserves the block's span (512 total instead
// of 16,384 contended). Thread 0 also recomputes the tiny padded prefix;
// block 0 fills tile_expert.
__global__ __launch_bounds__(256) void place_kernel(
    const int* __restrict__ winners, const float* __restrict__ wts,
    const int* __restrict__ counts, int* __restrict__ pos,
    int* __restrict__ token_id, float* __restrict__ pair_w,
    int* __restrict__ tile_expert) {
    __shared__ int po[E_ + 1];
    __shared__ int lcount[E_], lbase[E_];
    const int t = threadIdx.x;
    if (t < E_) lcount[t] = 0;
    if (t == 0) {
        int off = 0;
        po[0] = 0;
        #pragma unroll
        for (int e = 0; e < E_; ++e) {
            off += ((counts[e] + 127) >> 7) << 7;
            po[e + 1] = off;
        }
    }
    __syncthreads();
    if (blockIdx.x == 0 && t < MAXTILES) {
        int r = t * 128;
        int ee = -1;
        if (r < po[E_]) {
            ee = 0;
            while (r >= po[ee + 1]) ++ee;
        }
        tile_expert[t] = ee;
    }
    const int p = blockIdx.x * 256 + t;
    const int e = winners[p];
    const int rank = atomicAdd(&lcount[e], 1);  // LDS atomic
    __syncthreads();
    if (t < E_) {
        int c = lcount[t];
        lbase[t] = c ? atomicAdd(&pos[t], c) : 0;
    }
    __syncthreads();
    const int slot = po[e] + lbase[e] + rank;
    token_id[slot] = p >> 1;
    pair_w[slot] = wts[p];
}

// ---------------- Grouped GEMM, m97-style async staging + XOR swizzle ---------
// Round-2/4 proven structure, byte-identical (4 blocks/CU, implicit wave
// overlap, T1 XCD-bijective swizzle, PHASE2 K-split).
// PHASE2=false: hidden[r,:] = bf16(relu(h[tok(r)] @ W1T[e]^T)^2)  K=1024, N=4096
//               hidden K-dim stored permuted: p64 = lrow*4 + ni
// PHASE2=true : out[tok(r),:] += pair_w[r] * (hidden[r] @ W2T[e]^T) K=4096/KSPLIT
template <bool PHASE2>
__global__ __launch_bounds__(256, 4) void gemm_kernel(
    const u16* __restrict__ Amat, const u16* __restrict__ Bmat,
    const int* __restrict__ token_id, const float* __restrict__ pair_w,
    const int* __restrict__ tile_expert, u16* __restrict__ hidden,
    float* __restrict__ out, const u16* __restrict__ zeropage) {
    constexpr int Kdim = PHASE2 ? H_ : C_;            // row pitch of A and B
    constexpr int KRANGE = PHASE2 ? (H_ / KSPLIT) : C_;  // per-block K extent
    constexpr int NWGX = PHASE2 ? (C_ / BN) : (H_ / BN); // 8 or 32
    constexpr int NWG = NWGX * MAXTILES;              // 1088 or 4352 (%8==0)

    int bid = blockIdx.y * NWGX + blockIdx.x;
    bid = (bid & 7) * (NWG >> 3) + (bid >> 3);
    const int ct = bid % NWGX;
    const int rt = bid / NWGX;

    const int e = tile_expert[rt];
    if (e < 0) return;
    const int tid = threadIdx.x;
    const int w = tid >> 6;      // wave 0..3
    const int lane = tid & 63;
    const int n0 = ct * BN;
    const int kbase = PHASE2 ? blockIdx.z * KRANGE : 0;
    const u16* Bb = Bmat + (size_t)e * H_ * C_;

    __shared__ u16 As[BM * BK];  // 16 KB, [row][k], row = 128 B
    __shared__ u16 Bs[BN * BK];  // 16 KB, [n][k]

    const int sub = lane >> 3;
    const size_t koffB = (size_t)(((lane & 7) ^ sub) * 16);

    const char* abase[4];
    bool aval[4];
    const char* bbase[4];
    u16* adst[4];
    u16* bdst[4];
    #pragma unroll
    for (int j = 0; j < 4; ++j) {
        const int lrow32 = w * 32 + j * 8 + sub;
        const int grow = rt * BM + lrow32;
        if (PHASE2) {
            aval[j] = true;
            abase[j] = (const char*)(Amat + (size_t)grow * Kdim + kbase) + koffB;
        } else {
            int tok = token_id[grow];
            aval[j] = tok >= 0;
            abase[j] = (const char*)(Amat + (size_t)(tok < 0 ? 0 : tok) * Kdim) + koffB;
        }
        bbase[j] = (const char*)(Bb + (size_t)(n0 + lrow32) * Kdim + kbase) + koffB;
        adst[j] = &As[(w * 32 + j * 8) * BK];
        bdst[j] = &Bs[(w * 32 + j * 8) * BK];
    }

    const int wr = w >> 1, wc = w & 1;
    const int lrow = lane & 15;
    const int quad = lane >> 4;
    const int rsw = lrow & 7;  // read-side swizzle key

    f32x4 acc[4][4] = {};

    for (int k0 = 0; k0 < KRANGE; k0 += BK) {
        __syncthreads();
        const size_t kb = (size_t)k0 * 2;
        #pragma unroll
        for (int j = 0; j < 4; ++j)
            gld16(aval[j] ? abase[j] + kb : (const char*)zeropage, adst[j]);
        #pragma unroll
        for (int j = 0; j < 4; ++j)
            gld16(bbase[j] + kb, bdst[j]);
        __syncthreads();
        #pragma unroll
        for (int kk = 0; kk < 2; ++kk) {
            bf16x8 af[4], bfv[4];
            #pragma unroll
            for (int mi = 0; mi < 4; ++mi) {
                int row = wr * 64 + mi * 16 + lrow;
                int pch = (kk * 4 + quad) ^ rsw;
                af[mi] = *(const bf16x8*)&As[row * BK + pch * 8];
            }
            #pragma unroll
            for (int ni = 0; ni < 4; ++ni) {
                int row = wc * 64 + ni * 16 + lrow;
                int pch = (kk * 4 + quad) ^ rsw;
                bfv[ni] = *(const bf16x8*)&Bs[row * BK + pch * 8];
            }
            #pragma unroll
            for (int mi = 0; mi < 4; ++mi)
                #pragma unroll
                for (int ni = 0; ni < 4; ++ni)
                    acc[mi][ni] = __builtin_amdgcn_mfma_f32_16x16x32_bf16(
                        af[mi], bfv[ni], acc[mi][ni], 0, 0, 0);
        }
    }

    if (!PHASE2) {
        #pragma unroll
        for (int mi = 0; mi < 4; ++mi) {
            int rbase = rt * BM + wr * 64 + mi * 16 + quad * 4;
            #pragma unroll
            for (int j = 0; j < 4; ++j) {
                ushort4 o;
                float v0 = fmaxf(acc[mi][0][j], 0.0f);
                float v1 = fmaxf(acc[mi][1][j], 0.0f);
                float v2 = fmaxf(acc[mi][2][j], 0.0f);
                float v3 = fmaxf(acc[mi][3][j], 0.0f);
                o.x = f2bf(v0 * v0);
                o.y = f2bf(v1 * v1);
                o.z = f2bf(v2 * v2);
                o.w = f2bf(v3 * v3);
                *(ushort4*)&hidden[(size_t)(rbase + j) * H_ + n0 + wc * 64 + lrow * 4] = o;
            }
        }
    } else {
        #pragma unroll
        for (int mi = 0; mi < 4; ++mi) {
            int rbase = rt * BM + wr * 64 + mi * 16 + quad * 4;
            #pragma unroll
            for (int j = 0; j < 4; ++j) {
                int grow = rbase + j;
                int tok = token_id[grow];
                if (tok < 0) continue;
                float pw = pair_w[grow];
                #pragma unroll
                for (int ni = 0; ni < 4; ++ni) {
                    int col = n0 + wc * 64 + ni * 16 + lrow;
                    atomicAdd(&out[(size_t)tok * C_ + col], pw * acc[mi][ni][j]);
                }
            }
        }
    }
}

// ---------------- Launch ----------------
extern "C" void kernel_launch(void* const* d_in, const int* in_sizes, int n_in,
                              void* d_out, int out_size, void* d_ws, size_t ws_size,
                              hipStream_t stream) {
    const float* x = (const float*)d_in[0];
    const float* weights = (const float*)d_in[1];
    const float* gamma = (const float*)d_in[2];
    const float* beta = (const float*)d_in[3];
    const float* W1 = (const float*)d_in[4];
    const float* W2 = (const float*)d_in[5];
    const int* winners = (const int*)d_in[6];
    float* out = (float*)d_out;

    char* ws = (char*)d_ws;
    const size_t SZ_H = (size_t)NTOK * C_ * 2;           // 16 MB
    const size_t SZ_HID = (size_t)MAXROWS * H_ * 2;      // 136 MB
    const size_t SZ_WT = (size_t)E_ * H_ * C_ * 2;       // 64 MB each
    const size_t OFF_HID = SZ_H;
    const size_t OFF_W1T = OFF_HID + SZ_HID;
    const size_t OFF_W2T = OFF_W1T + SZ_WT;
    const size_t OFF_META = OFF_W2T + SZ_WT;

    u16* h = (u16*)ws;
    u16* hidden = (u16*)(ws + OFF_HID);
    u16* W1T = (u16*)(ws + OFF_W1T);
    u16* W2T = (u16*)(ws + OFF_W2T);
    int* meta = (int*)(ws + OFF_META);
    int* counts = meta;            // [0,8)
    int* pos = meta + 8;           // [8,16)
    // [16,32) reserved
    u16* zeropage = (u16*)(meta + 32);  // [32,48) 64 B, 16B-aligned
    int* tile_expert = meta + 48;  // [48,184)
    int* token_id = meta + 192;
    float* pair_w = (float*)(meta + 192 + MAXROWS);

    hipMemsetAsync(meta, 0, 192 * sizeof(int), stream);
    hipMemsetAsync(token_id, 0xFF, (size_t)MAXROWS * sizeof(int), stream);

    count_kernel<<<NPAIR / 256, 256, 0, stream>>>(winners, counts);
    ln_kernel<<<NTOK, 256, 0, stream>>>(x, gamma, beta, out, h);
    convert_transpose<false><<<dim3(H_ / 256, C_ / 64, E_), 256, 0, stream>>>(W1, W1T, C_, H_);
    convert_transpose<true><<<dim3(C_ / 256, H_ / 64, E_), 256, 0, stream>>>(W2, W2T, H_, C_);
    place_kernel<<<NPAIR / 256, 256, 0, stream>>>(winners, weights, counts, pos,
                                                  token_id, pair_w, tile_expert);
    gemm_kernel<false><<<dim3(H_ / BN, MAXTILES), 256, 0, stream>>>(
        h, W1T, token_id, pair_w, tile_expert, hidden, nullptr, zeropage);
    gemm_kernel<true><<<dim3(C_ / BN, MAXTILES, KSPLIT), 256, 0, stream>>>(
        hidden, W2T, token_id, pair_w, tile_expert, nullptr, out, zeropage);
}

// Round 6
// 715.483 us; speedup vs baseline: 1.3159x; 1.0185x over previous
//
#include <hip/hip_runtime.h>
#include <stddef.h>

typedef unsigned short u16;
typedef unsigned int u32;

#define B_ 4
#define T_ 2048
#define C_ 1024
#define E_ 8
#define H_ 4096
#define NTOK (B_ * T_)     // 8192
#define NPAIR (NTOK * 2)   // 16384
#define BM 128
#define BN 128
#define BK 64              // k-tile (bf16 elements); row = 128 B
#define KSPLIT 2           // phase2 K-split (atomics make this free)
#define MAXTILES 136       // ceil((16384 + 8*127)/128)
#define MAXROWS (MAXTILES * 128)  // 17408

// fused_pre block-range partition
#define NB_C1 2048   // convert W1: (4096/256) x (1024/64) x 8
#define NB_C2 2048   // convert W2: (1024/256) x (4096/64) x 8
#define NB_LN NTOK   // 8192
#define NB_CNT (NPAIR / 256)  // 64
#define NB_TID (MAXROWS / 1024)  // 17
#define NB_TOTAL (NB_C1 + NB_C2 + NB_LN + NB_CNT + NB_TID)

typedef __bf16 bf16x8 __attribute__((ext_vector_type(8)));
typedef float f32x4 __attribute__((ext_vector_type(4)));
typedef u16 u16x8 __attribute__((ext_vector_type(8)));

__device__ __forceinline__ u16 f2bf(float f) {
    union { float f; u32 u; } c;
    c.f = f;
    u32 r = c.u + 0x7FFFu + ((c.u >> 16) & 1u);  // round-to-nearest-even
    return (u16)(r >> 16);
}

// async global->LDS, 16B per lane; LDS dest = wave-uniform base + lane*16
__device__ __forceinline__ void gld16(const void* g, void* l) {
    __builtin_amdgcn_global_load_lds(
        (const __attribute__((address_space(1))) u32*)g,
        (__attribute__((address_space(3))) u32*)l, 16, 0, 0);
}

// ---------------- fused_pre bodies -------------------------------------------
// All segments are mutually independent streaming work; fusing them into one
// dispatch lets the CUs co-schedule ~470 MB of traffic instead of serializing
// 5 under-saturated dispatches. Each block takes exactly one branch (uniform),
// so intra-branch __syncthreads is safe.

// LayerNorm: h = bf16(LN(x)), out = x (residual base). Pure streaming.
__device__ __forceinline__ void ln_body(
    const float* __restrict__ x, const float* __restrict__ gamma,
    const float* __restrict__ beta, float* __restrict__ out,
    u16* __restrict__ h, int token, float* smf) {
    const int t = threadIdx.x;
    const float* xr = x + (size_t)token * C_;
    float4 v = *(const float4*)(xr + t * 4);
    float s = v.x + v.y + v.z + v.w;
    float ss = v.x * v.x + v.y * v.y + v.z * v.z + v.w * v.w;
    #pragma unroll
    for (int off = 32; off > 0; off >>= 1) {
        s += __shfl_down(s, off);
        ss += __shfl_down(ss, off);
    }
    float* ws_s = smf;       // [4]
    float* ws_q = smf + 4;   // [4]
    const int wave = t >> 6, lane = t & 63;
    if (lane == 0) { ws_s[wave] = s; ws_q[wave] = ss; }
    __syncthreads();
    float S = ws_s[0] + ws_s[1] + ws_s[2] + ws_s[3];
    float Q = ws_q[0] + ws_q[1] + ws_q[2] + ws_q[3];
    float mu = S * (1.0f / C_);
    float var = Q * (1.0f / C_) - mu * mu;
    float rstd = rsqrtf(var + 1e-5f);
    float4 g = *(const float4*)(gamma + t * 4);
    float4 b = *(const float4*)(beta + t * 4);
    ushort4 hv;
    hv.x = f2bf((v.x - mu) * rstd * g.x + b.x);
    hv.y = f2bf((v.y - mu) * rstd * g.y + b.y);
    hv.z = f2bf((v.z - mu) * rstd * g.z + b.z);
    hv.w = f2bf((v.w - mu) * rstd * g.w + b.w);
    *(float4*)(out + (size_t)token * C_ + t * 4) = v;
    *(ushort4*)(h + (size_t)token * C_ + t * 4) = hv;
}

// Weight convert+transpose fp32 [E][K][N] -> bf16 [E][N][K], streaming tiles
// of 64 k-rows x 256 n-cols (1KB contiguous wave reads, contiguous row writes,
// conflict-free pitch-258 LDS). PERM: src k-row permuted per 64-block by
// phi(r)=((r&3)<<4)|(r>>2) to match gemm1's packed hidden layout (W2 only).
template <bool PERM>
__device__ __forceinline__ void conv_body(
    const float* __restrict__ in, u16* __restrict__ outp, int K, int N,
    int bid, u16* sm) {
    const int nbx = N >> 8;              // N/256
    const int nby = K >> 6;              // K/64
    const int bx = bid % nbx;
    const int by = (bid / nbx) % nby;
    const int e = bid / (nbx * nby);
    const int k0 = by * 64, n0 = bx * 256;
    const int t = threadIdx.x;
    const float* src = in + (size_t)e * K * N;
    u16* dst = outp + (size_t)e * N * K;
    const int cw = t & 63;        // n-chunk (float4) within row
    const int rw = t >> 6;        // wave index = row offset within pass
    #pragma unroll
    for (int p = 0; p < 16; ++p) {
        const int r = p * 4 + rw;
        const int kr = PERM ? (((r & 3) << 4) | (r >> 2)) : r;
        float4 v = *(const float4*)(src + (size_t)(k0 + kr) * N + n0 + cw * 4);
        const int base = r * 258 + cw * 4;
        sm[base + 0] = f2bf(v.x);
        sm[base + 1] = f2bf(v.y);
        sm[base + 2] = f2bf(v.z);
        sm[base + 3] = f2bf(v.w);
    }
    __syncthreads();
    const u32* smw = (const u32*)sm;
    const int c = t & 7;          // 16B k-chunk within a dst row
    const int ro = t >> 3;        // row-pair offset within pass (0..31)
    #pragma unroll
    for (int p = 0; p < 4; ++p) {
        const int np = p * 32 + ro;          // dst rows 2np, 2np+1
        u16x8 lo, hi;
        #pragma unroll
        for (int m = 0; m < 8; ++m) {
            u32 wv = smw[(c * 8 + m) * 129 + np];
            lo[m] = (u16)(wv & 0xFFFFu);
            hi[m] = (u16)(wv >> 16);
        }
        *(u16x8*)(dst + (size_t)(n0 + 2 * np) * K + k0 + c * 8) = lo;
        *(u16x8*)(dst + (size_t)(n0 + 2 * np + 1) * K + k0 + c * 8) = hi;
    }
}

// Expert count: LDS histogram, 8 global atomics per block.
__device__ __forceinline__ void count_body(
    const int* __restrict__ winners, int* __restrict__ counts, int b, int* lc) {
    if (threadIdx.x < E_) lc[threadIdx.x] = 0;
    __syncthreads();
    atomicAdd(&lc[winners[b * 256 + threadIdx.x]], 1);  // LDS atomic
    __syncthreads();
    if (threadIdx.x < E_) {
        int c = lc[threadIdx.x];
        if (c) atomicAdd(&counts[threadIdx.x], c);
    }
}

__global__ __launch_bounds__(256) void fused_pre(
    const float* __restrict__ x, const float* __restrict__ gamma,
    const float* __restrict__ beta, float* __restrict__ out,
    u16* __restrict__ h, const int* __restrict__ winners,
    int* __restrict__ counts, const float* __restrict__ W1,
    u16* __restrict__ W1T, const float* __restrict__ W2,
    u16* __restrict__ W2T, int* __restrict__ token_id) {
    __shared__ u16 sm[64 * 258];  // conv buffer; reused by ln (floats) & count
    int b = blockIdx.x;
    if (b < NB_C1) { conv_body<false>(W1, W1T, C_, H_, b, sm); return; }
    b -= NB_C1;
    if (b < NB_C2) { conv_body<true>(W2, W2T, H_, C_, b, sm); return; }
    b -= NB_C2;
    if (b < NB_LN) { ln_body(x, gamma, beta, out, h, b, (float*)sm); return; }
    b -= NB_LN;
    if (b < NB_CNT) { count_body(winners, counts, b, (int*)sm); return; }
    b -= NB_CNT;
    const int p = (b * 256 + threadIdx.x) * 4;  // token_id = -1 fill
    if (p < MAXROWS) *(int4*)(token_id + p) = make_int4(-1, -1, -1, -1);
}

// ---------------- Placement: block-aggregated reservation --------------------
// Per-block LDS histogram gives each thread an intra-block rank; ONE global
// atomicAdd per (block, expert) reserves the block's span. Thread 0 recomputes
// the tiny padded prefix; block 0 fills tile_expert.
__global__ __launch_bounds__(256) void place_kernel(
    const int* __restrict__ winners, const float* __restrict__ wts,
    const int* __restrict__ counts, int* __restrict__ pos,
    int* __restrict__ token_id, float* __restrict__ pair_w,
    int* __restrict__ tile_expert) {
    __shared__ int po[E_ + 1];
    __shared__ int lcount[E_], lbase[E_];
    const int t = threadIdx.x;
    if (t < E_) lcount[t] = 0;
    if (t == 0) {
        int off = 0;
        po[0] = 0;
        #pragma unroll
        for (int e = 0; e < E_; ++e) {
            off += ((counts[e] + 127) >> 7) << 7;
            po[e + 1] = off;
        }
    }
    __syncthreads();
    if (blockIdx.x == 0 && t < MAXTILES) {
        int r = t * 128;
        int ee = -1;
        if (r < po[E_]) {
            ee = 0;
            while (r >= po[ee + 1]) ++ee;
        }
        tile_expert[t] = ee;
    }
    const int p = blockIdx.x * 256 + t;
    const int e = winners[p];
    const int rank = atomicAdd(&lcount[e], 1);  // LDS atomic
    __syncthreads();
    if (t < E_) {
        int c = lcount[t];
        lbase[t] = c ? atomicAdd(&pos[t], c) : 0;
    }
    __syncthreads();
    const int slot = po[e] + lbase[e] + rank;
    token_id[slot] = p >> 1;
    pair_w[slot] = wts[p];
}

// ---------------- Grouped GEMM, m97-style async staging + XOR swizzle ---------
// Round-2/4/5 proven structure, byte-identical (4 blocks/CU, implicit wave
// overlap, T1 XCD-bijective swizzle, PHASE2 K-split).
// PHASE2=false: hidden[r,:] = bf16(relu(h[tok(r)] @ W1T[e]^T)^2)  K=1024, N=4096
//               hidden K-dim stored permuted: p64 = lrow*4 + ni
// PHASE2=true : out[tok(r),:] += pair_w[r] * (hidden[r] @ W2T[e]^T) K=4096/KSPLIT
template <bool PHASE2>
__global__ __launch_bounds__(256, 4) void gemm_kernel(
    const u16* __restrict__ Amat, const u16* __restrict__ Bmat,
    const int* __restrict__ token_id, const float* __restrict__ pair_w,
    const int* __restrict__ tile_expert, u16* __restrict__ hidden,
    float* __restrict__ out, const u16* __restrict__ zeropage) {
    constexpr int Kdim = PHASE2 ? H_ : C_;            // row pitch of A and B
    constexpr int KRANGE = PHASE2 ? (H_ / KSPLIT) : C_;  // per-block K extent
    constexpr int NWGX = PHASE2 ? (C_ / BN) : (H_ / BN); // 8 or 32
    constexpr int NWG = NWGX * MAXTILES;              // 1088 or 4352 (%8==0)

    int bid = blockIdx.y * NWGX + blockIdx.x;
    bid = (bid & 7) * (NWG >> 3) + (bid >> 3);
    const int ct = bid % NWGX;
    const int rt = bid / NWGX;

    const int e = tile_expert[rt];
    if (e < 0) return;
    const int tid = threadIdx.x;
    const int w = tid >> 6;      // wave 0..3
    const int lane = tid & 63;
    const int n0 = ct * BN;
    const int kbase = PHASE2 ? blockIdx.z * KRANGE : 0;
    const u16* Bb = Bmat + (size_t)e * H_ * C_;

    __shared__ u16 As[BM * BK];  // 16 KB, [row][k], row = 128 B
    __shared__ u16 Bs[BN * BK];  // 16 KB, [n][k]

    const int sub = lane >> 3;
    const size_t koffB = (size_t)(((lane & 7) ^ sub) * 16);

    const char* abase[4];
    bool aval[4];
    const char* bbase[4];
    u16* adst[4];
    u16* bdst[4];
    #pragma unroll
    for (int j = 0; j < 4; ++j) {
        const int lrow32 = w * 32 + j * 8 + sub;
        const int grow = rt * BM + lrow32;
        if (PHASE2) {
            aval[j] = true;
            abase[j] = (const char*)(Amat + (size_t)grow * Kdim + kbase) + koffB;
        } else {
            int tok = token_id[grow];
            aval[j] = tok >= 0;
            abase[j] = (const char*)(Amat + (size_t)(tok < 0 ? 0 : tok) * Kdim) + koffB;
        }
        bbase[j] = (const char*)(Bb + (size_t)(n0 + lrow32) * Kdim + kbase) + koffB;
        adst[j] = &As[(w * 32 + j * 8) * BK];
        bdst[j] = &Bs[(w * 32 + j * 8) * BK];
    }

    const int wr = w >> 1, wc = w & 1;
    const int lrow = lane & 15;
    const int quad = lane >> 4;
    const int rsw = lrow & 7;  // read-side swizzle key

    f32x4 acc[4][4] = {};

    for (int k0 = 0; k0 < KRANGE; k0 += BK) {
        __syncthreads();
        const size_t kb = (size_t)k0 * 2;
        #pragma unroll
        for (int j = 0; j < 4; ++j)
            gld16(aval[j] ? abase[j] + kb : (const char*)zeropage, adst[j]);
        #pragma unroll
        for (int j = 0; j < 4; ++j)
            gld16(bbase[j] + kb, bdst[j]);
        __syncthreads();
        #pragma unroll
        for (int kk = 0; kk < 2; ++kk) {
            bf16x8 af[4], bfv[4];
            #pragma unroll
            for (int mi = 0; mi < 4; ++mi) {
                int row = wr * 64 + mi * 16 + lrow;
                int pch = (kk * 4 + quad) ^ rsw;
                af[mi] = *(const bf16x8*)&As[row * BK + pch * 8];
            }
            #pragma unroll
            for (int ni = 0; ni < 4; ++ni) {
                int row = wc * 64 + ni * 16 + lrow;
                int pch = (kk * 4 + quad) ^ rsw;
                bfv[ni] = *(const bf16x8*)&Bs[row * BK + pch * 8];
            }
            #pragma unroll
            for (int mi = 0; mi < 4; ++mi)
                #pragma unroll
                for (int ni = 0; ni < 4; ++ni)
                    acc[mi][ni] = __builtin_amdgcn_mfma_f32_16x16x32_bf16(
                        af[mi], bfv[ni], acc[mi][ni], 0, 0, 0);
        }
    }

    if (!PHASE2) {
        #pragma unroll
        for (int mi = 0; mi < 4; ++mi) {
            int rbase = rt * BM + wr * 64 + mi * 16 + quad * 4;
            #pragma unroll
            for (int j = 0; j < 4; ++j) {
                ushort4 o;
                float v0 = fmaxf(acc[mi][0][j], 0.0f);
                float v1 = fmaxf(acc[mi][1][j], 0.0f);
                float v2 = fmaxf(acc[mi][2][j], 0.0f);
                float v3 = fmaxf(acc[mi][3][j], 0.0f);
                o.x = f2bf(v0 * v0);
                o.y = f2bf(v1 * v1);
                o.z = f2bf(v2 * v2);
                o.w = f2bf(v3 * v3);
                *(ushort4*)&hidden[(size_t)(rbase + j) * H_ + n0 + wc * 64 + lrow * 4] = o;
            }
        }
    } else {
        #pragma unroll
        for (int mi = 0; mi < 4; ++mi) {
            int rbase = rt * BM + wr * 64 + mi * 16 + quad * 4;
            #pragma unroll
            for (int j = 0; j < 4; ++j) {
                int grow = rbase + j;
                int tok = token_id[grow];
                if (tok < 0) continue;
                float pw = pair_w[grow];
                #pragma unroll
                for (int ni = 0; ni < 4; ++ni) {
                    int col = n0 + wc * 64 + ni * 16 + lrow;
                    atomicAdd(&out[(size_t)tok * C_ + col], pw * acc[mi][ni][j]);
                }
            }
        }
    }
}

// ---------------- Launch ----------------
extern "C" void kernel_launch(void* const* d_in, const int* in_sizes, int n_in,
                              void* d_out, int out_size, void* d_ws, size_t ws_size,
                              hipStream_t stream) {
    const float* x = (const float*)d_in[0];
    const float* weights = (const float*)d_in[1];
    const float* gamma = (const float*)d_in[2];
    const float* beta = (const float*)d_in[3];
    const float* W1 = (const float*)d_in[4];
    const float* W2 = (const float*)d_in[5];
    const int* winners = (const int*)d_in[6];
    float* out = (float*)d_out;

    char* ws = (char*)d_ws;
    const size_t SZ_H = (size_t)NTOK * C_ * 2;           // 16 MB
    const size_t SZ_HID = (size_t)MAXROWS * H_ * 2;      // 136 MB
    const size_t SZ_WT = (size_t)E_ * H_ * C_ * 2;       // 64 MB each
    const size_t OFF_HID = SZ_H;
    const size_t OFF_W1T = OFF_HID + SZ_HID;
    const size_t OFF_W2T = OFF_W1T + SZ_WT;
    const size_t OFF_META = OFF_W2T + SZ_WT;

    u16* h = (u16*)ws;
    u16* hidden = (u16*)(ws + OFF_HID);
    u16* W1T = (u16*)(ws + OFF_W1T);
    u16* W2T = (u16*)(ws + OFF_W2T);
    int* meta = (int*)(ws + OFF_META);
    int* counts = meta;            // [0,8)
    int* pos = meta + 8;           // [8,16)
    // [16,32) reserved
    u16* zeropage = (u16*)(meta + 32);  // [32,48) 64 B, 16B-aligned
    int* tile_expert = meta + 48;  // [48,184)
    int* token_id = meta + 192;
    float* pair_w = (float*)(meta + 192 + MAXROWS);

    hipMemsetAsync(meta, 0, 192 * sizeof(int), stream);

    fused_pre<<<NB_TOTAL, 256, 0, stream>>>(x, gamma, beta, out, h, winners,
                                            counts, W1, W1T, W2, W2T, token_id);
    place_kernel<<<NPAIR / 256, 256, 0, stream>>>(winners, weights, counts, pos,
                                                  token_id, pair_w, tile_expert);
    gemm_kernel<false><<<dim3(H_ / BN, MAXTILES), 256, 0, stream>>>(
        h, W1T, token_id, pair_w, tile_expert, hidden, nullptr, zeropage);
    gemm_kernel<true><<<dim3(C_ / BN, MAXTILES, KSPLIT), 256, 0, stream>>>(
        hidden, W2T, token_id, pair_w, tile_expert, nullptr, out, zeropage);
}

// Round 7
// 705.070 us; speedup vs baseline: 1.3353x; 1.0148x over previous
//
#include <hip/hip_runtime.h>
#include <stddef.h>

typedef unsigned short u16;
typedef unsigned int u32;

#define B_ 4
#define T_ 2048
#define C_ 1024
#define E_ 8
#define H_ 4096
#define NTOK (B_ * T_)     // 8192
#define NPAIR (NTOK * 2)   // 16384
#define BM 128
#define BN 128
#define BK 64              // k-tile (bf16 elements); row = 128 B
#define KSPLIT 2           // phase2 K-split (atomics make this free)
#define MAXTILES 136       // ceil((16384 + 8*127)/128)
#define MAXROWS (MAXTILES * 128)  // 17408
#define NWG1 ((H_ / BN) * MAXTILES)  // 4352 gemm1 blocks

// fused_pre block-range partition (conv-W2 moved into gemm1's dispatch)
#define NB_C1 2048   // convert W1: (4096/256) x (1024/64) x 8
#define NB_C2 2048   // convert W2 (appended to gemm1 grid)
#define NB_LN NTOK   // 8192
#define NB_CNT (NPAIR / 256)  // 64
#define NB_TID (MAXROWS / 1024)  // 17
#define NB_TOTAL (NB_C1 + NB_LN + NB_CNT + NB_TID)

typedef __bf16 bf16x8 __attribute__((ext_vector_type(8)));
typedef float f32x4 __attribute__((ext_vector_type(4)));
typedef u16 u16x8 __attribute__((ext_vector_type(8)));

__device__ __forceinline__ u16 f2bf(float f) {
    union { float f; u32 u; } c;
    c.f = f;
    u32 r = c.u + 0x7FFFu + ((c.u >> 16) & 1u);  // round-to-nearest-even
    return (u16)(r >> 16);
}

// async global->LDS, 16B per lane; LDS dest = wave-uniform base + lane*16
__device__ __forceinline__ void gld16(const void* g, void* l) {
    __builtin_amdgcn_global_load_lds(
        (const __attribute__((address_space(1))) u32*)g,
        (__attribute__((address_space(3))) u32*)l, 16, 0, 0);
}

// ---------------- streaming bodies -------------------------------------------

// LayerNorm: h = bf16(LN(x)), out = x (residual base). Pure streaming.
__device__ __forceinline__ void ln_body(
    const float* __restrict__ x, const float* __restrict__ gamma,
    const float* __restrict__ beta, float* __restrict__ out,
    u16* __restrict__ h, int token, float* smf) {
    const int t = threadIdx.x;
    const float* xr = x + (size_t)token * C_;
    float4 v = *(const float4*)(xr + t * 4);
    float s = v.x + v.y + v.z + v.w;
    float ss = v.x * v.x + v.y * v.y + v.z * v.z + v.w * v.w;
    #pragma unroll
    for (int off = 32; off > 0; off >>= 1) {
        s += __shfl_down(s, off);
        ss += __shfl_down(ss, off);
    }
    float* ws_s = smf;       // [4]
    float* ws_q = smf + 4;   // [4]
    const int wave = t >> 6, lane = t & 63;
    if (lane == 0) { ws_s[wave] = s; ws_q[wave] = ss; }
    __syncthreads();
    float S = ws_s[0] + ws_s[1] + ws_s[2] + ws_s[3];
    float Q = ws_q[0] + ws_q[1] + ws_q[2] + ws_q[3];
    float mu = S * (1.0f / C_);
    float var = Q * (1.0f / C_) - mu * mu;
    float rstd = rsqrtf(var + 1e-5f);
    float4 g = *(const float4*)(gamma + t * 4);
    float4 b = *(const float4*)(beta + t * 4);
    ushort4 hv;
    hv.x = f2bf((v.x - mu) * rstd * g.x + b.x);
    hv.y = f2bf((v.y - mu) * rstd * g.y + b.y);
    hv.z = f2bf((v.z - mu) * rstd * g.z + b.z);
    hv.w = f2bf((v.w - mu) * rstd * g.w + b.w);
    *(float4*)(out + (size_t)token * C_ + t * 4) = v;
    *(ushort4*)(h + (size_t)token * C_ + t * 4) = hv;
}

// Weight convert+transpose fp32 [E][K][N] -> bf16 [E][N][K], streaming tiles
// of 64 k-rows x 256 n-cols (1KB contiguous wave reads, 8x128B row writes,
// conflict-free pitch-258 LDS). PERM: src k-row permuted per 64-block by
// phi(r)=((r&3)<<4)|(r>>2) to match gemm1's packed hidden layout (W2 only).
template <bool PERM>
__device__ __forceinline__ void conv_body(
    const float* __restrict__ in, u16* __restrict__ outp, int K, int N,
    int bid, u16* sm) {
    const int nbx = N >> 8;              // N/256
    const int nby = K >> 6;              // K/64
    const int bx = bid % nbx;
    const int by = (bid / nbx) % nby;
    const int e = bid / (nbx * nby);
    const int k0 = by * 64, n0 = bx * 256;
    const int t = threadIdx.x;
    const float* src = in + (size_t)e * K * N;
    u16* dst = outp + (size_t)e * N * K;
    const int cw = t & 63;        // n-chunk (float4) within row
    const int rw = t >> 6;        // wave index = row offset within pass
    #pragma unroll
    for (int p = 0; p < 16; ++p) {
        const int r = p * 4 + rw;
        const int kr = PERM ? (((r & 3) << 4) | (r >> 2)) : r;
        float4 v = *(const float4*)(src + (size_t)(k0 + kr) * N + n0 + cw * 4);
        const int base = r * 258 + cw * 4;
        sm[base + 0] = f2bf(v.x);
        sm[base + 1] = f2bf(v.y);
        sm[base + 2] = f2bf(v.z);
        sm[base + 3] = f2bf(v.w);
    }
    __syncthreads();
    const u32* smw = (const u32*)sm;
    const int c = t & 7;          // 16B k-chunk within a dst row
    const int ro = t >> 3;        // row-pair offset within pass (0..31)
    #pragma unroll
    for (int p = 0; p < 4; ++p) {
        const int np = p * 32 + ro;          // dst rows 2np, 2np+1
        u16x8 lo, hi;
        #pragma unroll
        for (int m = 0; m < 8; ++m) {
            u32 wv = smw[(c * 8 + m) * 129 + np];
            lo[m] = (u16)(wv & 0xFFFFu);
            hi[m] = (u16)(wv >> 16);
        }
        *(u16x8*)(dst + (size_t)(n0 + 2 * np) * K + k0 + c * 8) = lo;
        *(u16x8*)(dst + (size_t)(n0 + 2 * np + 1) * K + k0 + c * 8) = hi;
    }
}

// Expert count: LDS histogram, 8 global atomics per block.
__device__ __forceinline__ void count_body(
    const int* __restrict__ winners, int* __restrict__ counts, int b, int* lc) {
    if (threadIdx.x < E_) lc[threadIdx.x] = 0;
    __syncthreads();
    atomicAdd(&lc[winners[b * 256 + threadIdx.x]], 1);  // LDS atomic
    __syncthreads();
    if (threadIdx.x < E_) {
        int c = lc[threadIdx.x];
        if (c) atomicAdd(&counts[threadIdx.x], c);
    }
}

// ---------------- fused_pre: conv-W1 + LN + count + token_id fill ------------
__global__ __launch_bounds__(256) void fused_pre(
    const float* __restrict__ x, const float* __restrict__ gamma,
    const float* __restrict__ beta, float* __restrict__ out,
    u16* __restrict__ h, const int* __restrict__ winners,
    int* __restrict__ counts, const float* __restrict__ W1,
    u16* __restrict__ W1T, int* __restrict__ token_id) {
    __shared__ u16 sm[64 * 258];  // conv buffer; reused by ln (floats) & count
    int b = blockIdx.x;
    if (b < NB_C1) { conv_body<false>(W1, W1T, C_, H_, b, sm); return; }
    b -= NB_C1;
    if (b < NB_LN) { ln_body(x, gamma, beta, out, h, b, (float*)sm); return; }
    b -= NB_LN;
    if (b < NB_CNT) { count_body(winners, counts, b, (int*)sm); return; }
    b -= NB_CNT;
    const int p = (b * 256 + threadIdx.x) * 4;  // token_id = -1 fill
    if (p < MAXROWS) *(int4*)(token_id + p) = make_int4(-1, -1, -1, -1);
}

// ---------------- Placement: block-aggregated reservation --------------------
__global__ __launch_bounds__(256) void place_kernel(
    const int* __restrict__ winners, const float* __restrict__ wts,
    const int* __restrict__ counts, int* __restrict__ pos,
    int* __restrict__ token_id, float* __restrict__ pair_w,
    int* __restrict__ tile_expert) {
    __shared__ int po[E_ + 1];
    __shared__ int lcount[E_], lbase[E_];
    const int t = threadIdx.x;
    if (t < E_) lcount[t] = 0;
    if (t == 0) {
        int off = 0;
        po[0] = 0;
        #pragma unroll
        for (int e = 0; e < E_; ++e) {
            off += ((counts[e] + 127) >> 7) << 7;
            po[e + 1] = off;
        }
    }
    __syncthreads();
    if (blockIdx.x == 0 && t < MAXTILES) {
        int r = t * 128;
        int ee = -1;
        if (r < po[E_]) {
            ee = 0;
            while (r >= po[ee + 1]) ++ee;
        }
        tile_expert[t] = ee;
    }
    const int p = blockIdx.x * 256 + t;
    const int e = winners[p];
    const int rank = atomicAdd(&lcount[e], 1);  // LDS atomic
    __syncthreads();
    if (t < E_) {
        int c = lcount[t];
        lbase[t] = c ? atomicAdd(&pos[t], c) : 0;
    }
    __syncthreads();
    const int slot = po[e] + lbase[e] + rank;
    token_id[slot] = p >> 1;
    pair_w[slot] = wts[p];
}

// ---------------- Grouped GEMM body (round-2/4/5 proven, unchanged) ----------
// m97-style async staging + XOR swizzle, 4 blocks/CU implicit wave overlap,
// T1 XCD-bijective swizzle, PHASE2 K-split.
// PHASE2=false: hidden[r,:] = bf16(relu(h[tok(r)] @ W1T[e]^T)^2)  K=1024, N=4096
//               hidden K-dim stored permuted: p64 = lrow*4 + ni
// PHASE2=true : out[tok(r),:] += pair_w[r] * (hidden[r] @ W2T[e]^T) K=4096/KSPLIT
template <bool PHASE2>
__device__ __forceinline__ void gemm_body(
    const u16* __restrict__ Amat, const u16* __restrict__ Bmat,
    const int* __restrict__ token_id, const float* __restrict__ pair_w,
    const int* __restrict__ tile_expert, u16* __restrict__ hidden,
    float* __restrict__ out, const u16* __restrict__ zeropage,
    int bid0, int zi, u16* __restrict__ As, u16* __restrict__ Bs) {
    constexpr int Kdim = PHASE2 ? H_ : C_;            // row pitch of A and B
    constexpr int KRANGE = PHASE2 ? (H_ / KSPLIT) : C_;  // per-block K extent
    constexpr int NWGX = PHASE2 ? (C_ / BN) : (H_ / BN); // 8 or 32
    constexpr int NWG = NWGX * MAXTILES;              // 1088 or 4352 (%8==0)

    int bid = (bid0 & 7) * (NWG >> 3) + (bid0 >> 3);
    const int ct = bid % NWGX;
    const int rt = bid / NWGX;

    const int e = tile_expert[rt];
    if (e < 0) return;
    const int tid = threadIdx.x;
    const int w = tid >> 6;      // wave 0..3
    const int lane = tid & 63;
    const int n0 = ct * BN;
    const int kbase = PHASE2 ? zi * KRANGE : 0;
    const u16* Bb = Bmat + (size_t)e * H_ * C_;

    const int sub = lane >> 3;
    const size_t koffB = (size_t)(((lane & 7) ^ sub) * 16);

    const char* abase[4];
    bool aval[4];
    const char* bbase[4];
    u16* adst[4];
    u16* bdst[4];
    #pragma unroll
    for (int j = 0; j < 4; ++j) {
        const int lrow32 = w * 32 + j * 8 + sub;
        const int grow = rt * BM + lrow32;
        if (PHASE2) {
            aval[j] = true;
            abase[j] = (const char*)(Amat + (size_t)grow * Kdim + kbase) + koffB;
        } else {
            int tok = token_id[grow];
            aval[j] = tok >= 0;
            abase[j] = (const char*)(Amat + (size_t)(tok < 0 ? 0 : tok) * Kdim) + koffB;
        }
        bbase[j] = (const char*)(Bb + (size_t)(n0 + lrow32) * Kdim + kbase) + koffB;
        adst[j] = &As[(w * 32 + j * 8) * BK];
        bdst[j] = &Bs[(w * 32 + j * 8) * BK];
    }

    const int wr = w >> 1, wc = w & 1;
    const int lrow = lane & 15;
    const int quad = lane >> 4;
    const int rsw = lrow & 7;  // read-side swizzle key

    f32x4 acc[4][4] = {};

    for (int k0 = 0; k0 < KRANGE; k0 += BK) {
        __syncthreads();
        const size_t kb = (size_t)k0 * 2;
        #pragma unroll
        for (int j = 0; j < 4; ++j)
            gld16(aval[j] ? abase[j] + kb : (const char*)zeropage, adst[j]);
        #pragma unroll
        for (int j = 0; j < 4; ++j)
            gld16(bbase[j] + kb, bdst[j]);
        __syncthreads();
        #pragma unroll
        for (int kk = 0; kk < 2; ++kk) {
            bf16x8 af[4], bfv[4];
            #pragma unroll
            for (int mi = 0; mi < 4; ++mi) {
                int row = wr * 64 + mi * 16 + lrow;
                int pch = (kk * 4 + quad) ^ rsw;
                af[mi] = *(const bf16x8*)&As[row * BK + pch * 8];
            }
            #pragma unroll
            for (int ni = 0; ni < 4; ++ni) {
                int row = wc * 64 + ni * 16 + lrow;
                int pch = (kk * 4 + quad) ^ rsw;
                bfv[ni] = *(const bf16x8*)&Bs[row * BK + pch * 8];
            }
            #pragma unroll
            for (int mi = 0; mi < 4; ++mi)
                #pragma unroll
                for (int ni = 0; ni < 4; ++ni)
                    acc[mi][ni] = __builtin_amdgcn_mfma_f32_16x16x32_bf16(
                        af[mi], bfv[ni], acc[mi][ni], 0, 0, 0);
        }
    }

    if (!PHASE2) {
        #pragma unroll
        for (int mi = 0; mi < 4; ++mi) {
            int rbase = rt * BM + wr * 64 + mi * 16 + quad * 4;
            #pragma unroll
            for (int j = 0; j < 4; ++j) {
                ushort4 o;
                float v0 = fmaxf(acc[mi][0][j], 0.0f);
                float v1 = fmaxf(acc[mi][1][j], 0.0f);
                float v2 = fmaxf(acc[mi][2][j], 0.0f);
                float v3 = fmaxf(acc[mi][3][j], 0.0f);
                o.x = f2bf(v0 * v0);
                o.y = f2bf(v1 * v1);
                o.z = f2bf(v2 * v2);
                o.w = f2bf(v3 * v3);
                *(ushort4*)&hidden[(size_t)(rbase + j) * H_ + n0 + wc * 64 + lrow * 4] = o;
            }
        }
    } else {
        #pragma unroll
        for (int mi = 0; mi < 4; ++mi) {
            int rbase = rt * BM + wr * 64 + mi * 16 + quad * 4;
            #pragma unroll
            for (int j = 0; j < 4; ++j) {
                int grow = rbase + j;
                int tok = token_id[grow];
                if (tok < 0) continue;
                float pw = pair_w[grow];
                #pragma unroll
                for (int ni = 0; ni < 4; ++ni) {
                    int col = n0 + wc * 64 + ni * 16 + lrow;
                    atomicAdd(&out[(size_t)tok * C_ + col], pw * acc[mi][ni][j]);
                }
            }
        }
    }
}

// ---------------- gemm1 + conv-W2 soak (horizontal fusion) -------------------
// conv-W2 only gates gemm2, and gemm1 uses ~16% of HBM BW: append the 2048
// conv-W2 blocks to gemm1's grid so their 192 MB streams under gemm1's
// compute. LDS union = 33 KB -> still 4 blocks/CU.
__global__ __launch_bounds__(256, 4) void gemm1_conv(
    const u16* __restrict__ h, const u16* __restrict__ W1T,
    const int* __restrict__ token_id, const float* __restrict__ pair_w,
    const int* __restrict__ tile_expert, u16* __restrict__ hidden,
    const u16* __restrict__ zeropage, const float* __restrict__ W2,
    u16* __restrict__ W2T) {
    __shared__ u16 smu[64 * 258];  // 33 KB union: gemm uses first 32 KB
    const int b = blockIdx.x;
    if (b < NWG1) {
        gemm_body<false>(h, W1T, token_id, pair_w, tile_expert, hidden,
                         nullptr, zeropage, b, 0, smu, smu + BM * BK);
    } else {
        conv_body<true>(W2, W2T, H_, C_, b - NWG1, smu);
    }
}

// ---------------- phase2 wrapper (unchanged structure) -----------------------
__global__ __launch_bounds__(256, 4) void gemm2_kernel(
    const u16* __restrict__ hidden, const u16* __restrict__ W2T,
    const int* __restrict__ token_id, const float* __restrict__ pair_w,
    const int* __restrict__ tile_expert, float* __restrict__ out,
    const u16* __restrict__ zeropage) {
    __shared__ u16 As[BM * BK];
    __shared__ u16 Bs[BN * BK];
    const int bid = blockIdx.y * (C_ / BN) + blockIdx.x;
    gemm_body<true>(hidden, W2T, token_id, pair_w, tile_expert, nullptr, out,
                    zeropage, bid, blockIdx.z, As, Bs);
}

// ---------------- Launch ----------------
extern "C" void kernel_launch(void* const* d_in, const int* in_sizes, int n_in,
                              void* d_out, int out_size, void* d_ws, size_t ws_size,
                              hipStream_t stream) {
    const float* x = (const float*)d_in[0];
    const float* weights = (const float*)d_in[1];
    const float* gamma = (const float*)d_in[2];
    const float* beta = (const float*)d_in[3];
    const float* W1 = (const float*)d_in[4];
    const float* W2 = (const float*)d_in[5];
    const int* winners = (const int*)d_in[6];
    float* out = (float*)d_out;

    char* ws = (char*)d_ws;
    const size_t SZ_H = (size_t)NTOK * C_ * 2;           // 16 MB
    const size_t SZ_HID = (size_t)MAXROWS * H_ * 2;      // 136 MB
    const size_t SZ_WT = (size_t)E_ * H_ * C_ * 2;       // 64 MB each
    const size_t OFF_HID = SZ_H;
    const size_t OFF_W1T = OFF_HID + SZ_HID;
    const size_t OFF_W2T = OFF_W1T + SZ_WT;
    const size_t OFF_META = OFF_W2T + SZ_WT;

    u16* h = (u16*)ws;
    u16* hidden = (u16*)(ws + OFF_HID);
    u16* W1T = (u16*)(ws + OFF_W1T);
    u16* W2T = (u16*)(ws + OFF_W2T);
    int* meta = (int*)(ws + OFF_META);
    int* counts = meta;            // [0,8)
    int* pos = meta + 8;           // [8,16)
    // [16,32) reserved
    u16* zeropage = (u16*)(meta + 32);  // [32,48) 64 B, 16B-aligned
    int* tile_expert = meta + 48;  // [48,184)
    int* token_id = meta + 192;
    float* pair_w = (float*)(meta + 192 + MAXROWS);

    hipMemsetAsync(meta, 0, 192 * sizeof(int), stream);

    fused_pre<<<NB_TOTAL, 256, 0, stream>>>(x, gamma, beta, out, h, winners,
                                            counts, W1, W1T, token_id);
    place_kernel<<<NPAIR / 256, 256, 0, stream>>>(winners, weights, counts, pos,
                                                  token_id, pair_w, tile_expert);
    gemm1_conv<<<NWG1 + NB_C2, 256, 0, stream>>>(
        h, W1T, token_id, pair_w, tile_expert, hidden, zeropage, W2, W2T);
    gemm2_kernel<<<dim3(C_ / BN, MAXTILES, KSPLIT), 256, 0, stream>>>(
        hidden, W2T, token_id, pair_w, tile_expert, out, zeropage);
}

// Round 8
// 696.403 us; speedup vs baseline: 1.3520x; 1.0124x over previous
//
#include <hip/hip_runtime.h>
#include <stddef.h>

typedef unsigned short u16;
typedef unsigned int u32;

#define B_ 4
#define T_ 2048
#define C_ 1024
#define E_ 8
#define H_ 4096
#define NTOK (B_ * T_)     // 8192
#define NPAIR (NTOK * 2)   // 16384
#define BM 128
#define BN 128
#define BK 64              // k-tile (bf16 elements); row = 128 B
#define KSPLIT 2           // phase2 K-split (atomics make this free)
#define MAXTILES 136       // ceil((16384 + 8*127)/128)
#define MAXROWS (MAXTILES * 128)  // 17408
#define NWG1 ((H_ / BN) * MAXTILES)  // 4352 gemm1 blocks

// gemm1_conv appended segments
#define NB_C2 2048   // convert W2
#define NB_CP 1024   // out = x copy (8192 floats/block)

// fused_pre block-range partition
#define NB_C1 2048   // convert W1: (4096/256) x (1024/64) x 8
#define NB_LN NTOK   // 8192
#define NB_CNT (NPAIR / 256)  // 64
#define NB_TID (MAXROWS / 1024)  // 17
#define NB_TOTAL (NB_C1 + NB_LN + NB_CNT + NB_TID)

typedef __bf16 bf16x8 __attribute__((ext_vector_type(8)));
typedef float f32x4 __attribute__((ext_vector_type(4)));
typedef u16 u16x8 __attribute__((ext_vector_type(8)));

__device__ __forceinline__ u16 f2bf(float f) {
    union { float f; u32 u; } c;
    c.f = f;
    u32 r = c.u + 0x7FFFu + ((c.u >> 16) & 1u);  // round-to-nearest-even
    return (u16)(r >> 16);
}

// pack two floats to bf16x2 in a u32 via native RNE casts (compiler can fuse
// to v_cvt_pk_bf16_f32)
__device__ __forceinline__ u32 pk2bf(float a, float b) {
    union { __bf16 h; u16 u; } x, y;
    x.h = (__bf16)a;
    y.h = (__bf16)b;
    return (u32)x.u | ((u32)y.u << 16);
}

// async global->LDS, 16B per lane; LDS dest = wave-uniform base + lane*16
__device__ __forceinline__ void gld16(const void* g, void* l) {
    __builtin_amdgcn_global_load_lds(
        (const __attribute__((address_space(1))) u32*)g,
        (__attribute__((address_space(3))) u32*)l, 16, 0, 0);
}

// ---------------- streaming bodies -------------------------------------------

// LayerNorm: h = bf16(LN(x)). The out=x residual copy moved to gemm1_conv.
__device__ __forceinline__ void ln_body(
    const float* __restrict__ x, const float* __restrict__ gamma,
    const float* __restrict__ beta, u16* __restrict__ h, int token,
    float* smf) {
    const int t = threadIdx.x;
    const float* xr = x + (size_t)token * C_;
    float4 v = *(const float4*)(xr + t * 4);
    float s = v.x + v.y + v.z + v.w;
    float ss = v.x * v.x + v.y * v.y + v.z * v.z + v.w * v.w;
    #pragma unroll
    for (int off = 32; off > 0; off >>= 1) {
        s += __shfl_down(s, off);
        ss += __shfl_down(ss, off);
    }
    float* ws_s = smf;       // [4]
    float* ws_q = smf + 4;   // [4]
    const int wave = t >> 6, lane = t & 63;
    if (lane == 0) { ws_s[wave] = s; ws_q[wave] = ss; }
    __syncthreads();
    float S = ws_s[0] + ws_s[1] + ws_s[2] + ws_s[3];
    float Q = ws_q[0] + ws_q[1] + ws_q[2] + ws_q[3];
    float mu = S * (1.0f / C_);
    float var = Q * (1.0f / C_) - mu * mu;
    float rstd = rsqrtf(var + 1e-5f);
    float4 g = *(const float4*)(gamma + t * 4);
    float4 b = *(const float4*)(beta + t * 4);
    ushort4 hv;
    hv.x = f2bf((v.x - mu) * rstd * g.x + b.x);
    hv.y = f2bf((v.y - mu) * rstd * g.y + b.y);
    hv.z = f2bf((v.z - mu) * rstd * g.z + b.z);
    hv.w = f2bf((v.w - mu) * rstd * g.w + b.w);
    *(ushort4*)(h + (size_t)token * C_ + t * 4) = hv;
}

// Weight convert+transpose fp32 [E][K][N] -> bf16 [E][N][K], streaming tiles
// of 64 k-rows x 256 n-cols (1KB contiguous wave reads, 8x128B row writes,
// conflict-free pitch-258 LDS; u32-packed LDS writes). PERM: src k-row
// permuted per 64-block by phi(r)=((r&3)<<4)|(r>>2) (W2 only).
template <bool PERM>
__device__ __forceinline__ void conv_body(
    const float* __restrict__ in, u16* __restrict__ outp, int K, int N,
    int bid, u16* sm) {
    const int nbx = N >> 8;              // N/256
    const int nby = K >> 6;              // K/64
    const int bx = bid % nbx;
    const int by = (bid / nbx) % nby;
    const int e = bid / (nbx * nby);
    const int k0 = by * 64, n0 = bx * 256;
    const int t = threadIdx.x;
    const float* src = in + (size_t)e * K * N;
    u16* dst = outp + (size_t)e * N * K;
    const int cw = t & 63;        // n-chunk (float4) within row
    const int rw = t >> 6;        // wave index = row offset within pass
    #pragma unroll
    for (int p = 0; p < 16; ++p) {
        const int r = p * 4 + rw;
        const int kr = PERM ? (((r & 3) << 4) | (r >> 2)) : r;
        float4 v = *(const float4*)(src + (size_t)(k0 + kr) * N + n0 + cw * 4);
        const int base = r * 258 + cw * 4;  // u16 idx; byte addr 4-B aligned
        *(u32*)&sm[base + 0] = pk2bf(v.x, v.y);
        *(u32*)&sm[base + 2] = pk2bf(v.z, v.w);
    }
    __syncthreads();
    const u32* smw = (const u32*)sm;
    const int c = t & 7;          // 16B k-chunk within a dst row
    const int ro = t >> 3;        // row-pair offset within pass (0..31)
    #pragma unroll
    for (int p = 0; p < 4; ++p) {
        const int np = p * 32 + ro;          // dst rows 2np, 2np+1
        u16x8 lo, hi;
        #pragma unroll
        for (int m = 0; m < 8; ++m) {
            u32 wv = smw[(c * 8 + m) * 129 + np];
            lo[m] = (u16)(wv & 0xFFFFu);
            hi[m] = (u16)(wv >> 16);
        }
        *(u16x8*)(dst + (size_t)(n0 + 2 * np) * K + k0 + c * 8) = lo;
        *(u16x8*)(dst + (size_t)(n0 + 2 * np + 1) * K + k0 + c * 8) = hi;
    }
}

// Expert count: LDS histogram, 8 global atomics per block.
__device__ __forceinline__ void count_body(
    const int* __restrict__ winners, int* __restrict__ counts, int b, int* lc) {
    if (threadIdx.x < E_) lc[threadIdx.x] = 0;
    __syncthreads();
    atomicAdd(&lc[winners[b * 256 + threadIdx.x]], 1);  // LDS atomic
    __syncthreads();
    if (threadIdx.x < E_) {
        int c = lc[threadIdx.x];
        if (c) atomicAdd(&counts[threadIdx.x], c);
    }
}

// out = x residual copy: 8192 floats (2048 float4) per block, 1KB/wave-read.
__device__ __forceinline__ void copy_body(
    const float* __restrict__ x, float* __restrict__ out, int b) {
    const int t = threadIdx.x;
    const float4* src = (const float4*)x + (size_t)b * 2048;
    float4* dst = (float4*)out + (size_t)b * 2048;
    #pragma unroll
    for (int i = 0; i < 8; ++i) dst[i * 256 + t] = src[i * 256 + t];
}

// ---------------- fused_pre: conv-W1 + LN + count + token_id fill ------------
__global__ __launch_bounds__(256) void fused_pre(
    const float* __restrict__ x, const float* __restrict__ gamma,
    const float* __restrict__ beta, u16* __restrict__ h,
    const int* __restrict__ winners, int* __restrict__ counts,
    const float* __restrict__ W1, u16* __restrict__ W1T,
    int* __restrict__ token_id) {
    __shared__ u16 sm[64 * 258];  // conv buffer; reused by ln (floats) & count
    int b = blockIdx.x;
    if (b < NB_C1) { conv_body<false>(W1, W1T, C_, H_, b, sm); return; }
    b -= NB_C1;
    if (b < NB_LN) { ln_body(x, gamma, beta, h, b, (float*)sm); return; }
    b -= NB_LN;
    if (b < NB_CNT) { count_body(winners, counts, b, (int*)sm); return; }
    b -= NB_CNT;
    const int p = (b * 256 + threadIdx.x) * 4;  // token_id = -1 fill
    if (p < MAXROWS) *(int4*)(token_id + p) = make_int4(-1, -1, -1, -1);
}

// ---------------- Placement: block-aggregated reservation --------------------
__global__ __launch_bounds__(256) void place_kernel(
    const int* __restrict__ winners, const float* __restrict__ wts,
    const int* __restrict__ counts, int* __restrict__ pos,
    int* __restrict__ token_id, float* __restrict__ pair_w,
    int* __restrict__ tile_expert) {
    __shared__ int po[E_ + 1];
    __shared__ int lcount[E_], lbase[E_];
    const int t = threadIdx.x;
    if (t < E_) lcount[t] = 0;
    if (t == 0) {
        int off = 0;
        po[0] = 0;
        #pragma unroll
        for (int e = 0; e < E_; ++e) {
            off += ((counts[e] + 127) >> 7) << 7;
            po[e + 1] = off;
        }
    }
    __syncthreads();
    if (blockIdx.x == 0 && t < MAXTILES) {
        int r = t * 128;
        int ee = -1;
        if (r < po[E_]) {
            ee = 0;
            while (r >= po[ee + 1]) ++ee;
        }
        tile_expert[t] = ee;
    }
    const int p = blockIdx.x * 256 + t;
    const int e = winners[p];
    const int rank = atomicAdd(&lcount[e], 1);  // LDS atomic
    __syncthreads();
    if (t < E_) {
        int c = lcount[t];
        lbase[t] = c ? atomicAdd(&pos[t], c) : 0;
    }
    __syncthreads();
    const int slot = po[e] + lbase[e] + rank;
    token_id[slot] = p >> 1;
    pair_w[slot] = wts[p];
}

// ---------------- Grouped GEMM body (round-2/4/5 proven, unchanged) ----------
// m97-style async staging + XOR swizzle, 4 blocks/CU implicit wave overlap,
// T1 XCD-bijective swizzle, PHASE2 K-split.
// PHASE2=false: hidden[r,:] = bf16(relu(h[tok(r)] @ W1T[e]^T)^2)  K=1024, N=4096
//               hidden K-dim stored permuted: p64 = lrow*4 + ni
// PHASE2=true : out[tok(r),:] += pair_w[r] * (hidden[r] @ W2T[e]^T) K=4096/KSPLIT
template <bool PHASE2>
__device__ __forceinline__ void gemm_body(
    const u16* __restrict__ Amat, const u16* __restrict__ Bmat,
    const int* __restrict__ token_id, const float* __restrict__ pair_w,
    const int* __restrict__ tile_expert, u16* __restrict__ hidden,
    float* __restrict__ out, const u16* __restrict__ zeropage,
    int bid0, int zi, u16* __restrict__ As, u16* __restrict__ Bs) {
    constexpr int Kdim = PHASE2 ? H_ : C_;            // row pitch of A and B
    constexpr int KRANGE = PHASE2 ? (H_ / KSPLIT) : C_;  // per-block K extent
    constexpr int NWGX = PHASE2 ? (C_ / BN) : (H_ / BN); // 8 or 32
    constexpr int NWG = NWGX * MAXTILES;              // 1088 or 4352 (%8==0)

    int bid = (bid0 & 7) * (NWG >> 3) + (bid0 >> 3);
    const int ct = bid % NWGX;
    const int rt = bid / NWGX;

    const int e = tile_expert[rt];
    if (e < 0) return;
    const int tid = threadIdx.x;
    const int w = tid >> 6;      // wave 0..3
    const int lane = tid & 63;
    const int n0 = ct * BN;
    const int kbase = PHASE2 ? zi * KRANGE : 0;
    const u16* Bb = Bmat + (size_t)e * H_ * C_;

    const int sub = lane >> 3;
    const size_t koffB = (size_t)(((lane & 7) ^ sub) * 16);

    const char* abase[4];
    bool aval[4];
    const char* bbase[4];
    u16* adst[4];
    u16* bdst[4];
    #pragma unroll
    for (int j = 0; j < 4; ++j) {
        const int lrow32 = w * 32 + j * 8 + sub;
        const int grow = rt * BM + lrow32;
        if (PHASE2) {
            aval[j] = true;
            abase[j] = (const char*)(Amat + (size_t)grow * Kdim + kbase) + koffB;
        } else {
            int tok = token_id[grow];
            aval[j] = tok >= 0;
            abase[j] = (const char*)(Amat + (size_t)(tok < 0 ? 0 : tok) * Kdim) + koffB;
        }
        bbase[j] = (const char*)(Bb + (size_t)(n0 + lrow32) * Kdim + kbase) + koffB;
        adst[j] = &As[(w * 32 + j * 8) * BK];
        bdst[j] = &Bs[(w * 32 + j * 8) * BK];
    }

    const int wr = w >> 1, wc = w & 1;
    const int lrow = lane & 15;
    const int quad = lane >> 4;
    const int rsw = lrow & 7;  // read-side swizzle key

    f32x4 acc[4][4] = {};

    for (int k0 = 0; k0 < KRANGE; k0 += BK) {
        __syncthreads();
        const size_t kb = (size_t)k0 * 2;
        #pragma unroll
        for (int j = 0; j < 4; ++j)
            gld16(aval[j] ? abase[j] + kb : (const char*)zeropage, adst[j]);
        #pragma unroll
        for (int j = 0; j < 4; ++j)
            gld16(bbase[j] + kb, bdst[j]);
        __syncthreads();
        #pragma unroll
        for (int kk = 0; kk < 2; ++kk) {
            bf16x8 af[4], bfv[4];
            #pragma unroll
            for (int mi = 0; mi < 4; ++mi) {
                int row = wr * 64 + mi * 16 + lrow;
                int pch = (kk * 4 + quad) ^ rsw;
                af[mi] = *(const bf16x8*)&As[row * BK + pch * 8];
            }
            #pragma unroll
            for (int ni = 0; ni < 4; ++ni) {
                int row = wc * 64 + ni * 16 + lrow;
                int pch = (kk * 4 + quad) ^ rsw;
                bfv[ni] = *(const bf16x8*)&Bs[row * BK + pch * 8];
            }
            #pragma unroll
            for (int mi = 0; mi < 4; ++mi)
                #pragma unroll
                for (int ni = 0; ni < 4; ++ni)
                    acc[mi][ni] = __builtin_amdgcn_mfma_f32_16x16x32_bf16(
                        af[mi], bfv[ni], acc[mi][ni], 0, 0, 0);
        }
    }

    if (!PHASE2) {
        #pragma unroll
        for (int mi = 0; mi < 4; ++mi) {
            int rbase = rt * BM + wr * 64 + mi * 16 + quad * 4;
            #pragma unroll
            for (int j = 0; j < 4; ++j) {
                ushort4 o;
                float v0 = fmaxf(acc[mi][0][j], 0.0f);
                float v1 = fmaxf(acc[mi][1][j], 0.0f);
                float v2 = fmaxf(acc[mi][2][j], 0.0f);
                float v3 = fmaxf(acc[mi][3][j], 0.0f);
                o.x = f2bf(v0 * v0);
                o.y = f2bf(v1 * v1);
                o.z = f2bf(v2 * v2);
                o.w = f2bf(v3 * v3);
                *(ushort4*)&hidden[(size_t)(rbase + j) * H_ + n0 + wc * 64 + lrow * 4] = o;
            }
        }
    } else {
        #pragma unroll
        for (int mi = 0; mi < 4; ++mi) {
            int rbase = rt * BM + wr * 64 + mi * 16 + quad * 4;
            #pragma unroll
            for (int j = 0; j < 4; ++j) {
                int grow = rbase + j;
                int tok = token_id[grow];
                if (tok < 0) continue;
                float pw = pair_w[grow];
                #pragma unroll
                for (int ni = 0; ni < 4; ++ni) {
                    int col = n0 + wc * 64 + ni * 16 + lrow;
                    atomicAdd(&out[(size_t)tok * C_ + col], pw * acc[mi][ni][j]);
                }
            }
        }
    }
}

// ---------------- gemm1 + conv-W2 + out=x soak (horizontal fusion) -----------
// conv-W2 and the residual copy only gate gemm2; gemm1 uses ~16% of HBM BW,
// so their ~256 MB streams free under gemm1's compute. LDS union 33 KB.
__global__ __launch_bounds__(256, 4) void gemm1_conv(
    const u16* __restrict__ h, const u16* __restrict__ W1T,
    const int* __restrict__ token_id, const float* __restrict__ pair_w,
    const int* __restrict__ tile_expert, u16* __restrict__ hidden,
    const u16* __restrict__ zeropage, const float* __restrict__ W2,
    u16* __restrict__ W2T, const float* __restrict__ x,
    float* __restrict__ out) {
    __shared__ u16 smu[64 * 258];  // 33 KB union: gemm uses first 32 KB
    const int b = blockIdx.x;
    if (b < NWG1) {
        gemm_body<false>(h, W1T, token_id, pair_w, tile_expert, hidden,
                         nullptr, zeropage, b, 0, smu, smu + BM * BK);
    } else if (b < NWG1 + NB_C2) {
        conv_body<true>(W2, W2T, H_, C_, b - NWG1, smu);
    } else {
        copy_body(x, out, b - NWG1 - NB_C2);
    }
}

// ---------------- phase2 wrapper (unchanged structure) -----------------------
__global__ __launch_bounds__(256, 4) void gemm2_kernel(
    const u16* __restrict__ hidden, const u16* __restrict__ W2T,
    const int* __restrict__ token_id, const float* __restrict__ pair_w,
    const int* __restrict__ tile_expert, float* __restrict__ out,
    const u16* __restrict__ zeropage) {
    __shared__ u16 As[BM * BK];
    __shared__ u16 Bs[BN * BK];
    const int bid = blockIdx.y * (C_ / BN) + blockIdx.x;
    gemm_body<true>(hidden, W2T, token_id, pair_w, tile_expert, nullptr, out,
                    zeropage, bid, blockIdx.z, As, Bs);
}

// ---------------- Launch ----------------
extern "C" void kernel_launch(void* const* d_in, const int* in_sizes, int n_in,
                              void* d_out, int out_size, void* d_ws, size_t ws_size,
                              hipStream_t stream) {
    const float* x = (const float*)d_in[0];
    const float* weights = (const float*)d_in[1];
    const float* gamma = (const float*)d_in[2];
    const float* beta = (const float*)d_in[3];
    const float* W1 = (const float*)d_in[4];
    const float* W2 = (const float*)d_in[5];
    const int* winners = (const int*)d_in[6];
    float* out = (float*)d_out;

    char* ws = (char*)d_ws;
    const size_t SZ_H = (size_t)NTOK * C_ * 2;           // 16 MB
    const size_t SZ_HID = (size_t)MAXROWS * H_ * 2;      // 136 MB
    const size_t SZ_WT = (size_t)E_ * H_ * C_ * 2;       // 64 MB each
    const size_t OFF_HID = SZ_H;
    const size_t OFF_W1T = OFF_HID + SZ_HID;
    const size_t OFF_W2T = OFF_W1T + SZ_WT;
    const size_t OFF_META = OFF_W2T + SZ_WT;

    u16* h = (u16*)ws;
    u16* hidden = (u16*)(ws + OFF_HID);
    u16* W1T = (u16*)(ws + OFF_W1T);
    u16* W2T = (u16*)(ws + OFF_W2T);
    int* meta = (int*)(ws + OFF_META);
    int* counts = meta;            // [0,8)
    int* pos = meta + 8;           // [8,16)
    // [16,32) reserved
    u16* zeropage = (u16*)(meta + 32);  // [32,48) 64 B, 16B-aligned
    int* tile_expert = meta + 48;  // [48,184)
    int* token_id = meta + 192;
    float* pair_w = (float*)(meta + 192 + MAXROWS);

    hipMemsetAsync(meta, 0, 192 * sizeof(int), stream);

    fused_pre<<<NB_TOTAL, 256, 0, stream>>>(x, gamma, beta, h, winners,
                                            counts, W1, W1T, token_id);
    place_kernel<<<NPAIR / 256, 256, 0, stream>>>(winners, weights, counts, pos,
                                                  token_id, pair_w, tile_expert);
    gemm1_conv<<<NWG1 + NB_C2 + NB_CP, 256, 0, stream>>>(
        h, W1T, token_id, pair_w, tile_expert, hidden, zeropage, W2, W2T, x, out);
    gemm2_kernel<<<dim3(C_ / BN, MAXTILES, KSPLIT), 256, 0, stream>>>(
        hidden, W2T, token_id, pair_w, tile_expert, out, zeropage);
}